// Round 1
// baseline (947.631 us; speedup 1.0000x reference)
//
#include <hip/hip_runtime.h>
#include <math.h>

#define TW 3072
#define TH 3072
#define NPIX (TW*TH)

// ---------------- init scalars ----------------
// scal[0]=magmax bits, scal[1]=edmin bits, scal[2]=edmax bits,
// scal[3]=max hist count, scal[4]=min nonzero hist count
__global__ void k_init(unsigned* scal) {
    if (threadIdx.x == 0) {
        scal[0] = 0u;
        scal[1] = 0x7F800000u;  // +inf
        scal[2] = 0u;
        scal[3] = 0u;
        scal[4] = 0xFFFFFFFFu;
    }
}

// ---------------- pass 1: gray + code + histogram ----------------
__global__ void k_pre(const float* __restrict__ img, float* __restrict__ gray,
                      unsigned short* __restrict__ code, unsigned* __restrict__ hist) {
    int stride = gridDim.x * blockDim.x;
    for (int p = blockIdx.x * blockDim.x + threadIdx.x; p < NPIX; p += stride) {
        float r = img[p], g = img[p + NPIX], b = img[p + 2 * NPIX];
        // gray = 0.299*r + 0.587*g + 0.114*b, no FMA contraction (threshold-sensitive path)
        float gy = __fadd_rn(__fadd_rn(__fmul_rn(0.299f, r), __fmul_rn(0.587f, g)),
                             __fmul_rn(0.114f, b));
        gray[p] = gy;
        int ir = min(max((int)rintf(__fmul_rn(r, 31.f)), 0), 31);
        int ig = min(max((int)rintf(__fmul_rn(g, 31.f)), 0), 31);
        int ib = min(max((int)rintf(__fmul_rn(b, 31.f)), 0), 31);
        int c = ir * 1024 + ig * 32 + ib;
        code[p] = (unsigned short)c;
        atomicAdd(&hist[c], 1u);
    }
}

// ---------------- pass 2: 5x5 box blur (zero pad, /25 everywhere) ----------------
__global__ void k_box(const float* __restrict__ g, float* __restrict__ out) {
    int j = blockIdx.x * blockDim.x + threadIdx.x;
    int i = blockIdx.y;
    float acc = 0.f;
#pragma unroll
    for (int a = -2; a <= 2; a++) {
        int y = i + a;
        if ((unsigned)y >= TH) continue;
#pragma unroll
        for (int b = -2; b <= 2; b++) {
            int x = j + b;
            if ((unsigned)x >= TW) continue;
            acc = __fadd_rn(acc, __fmul_rn(g[y * TW + x], 0.04f));
        }
    }
    out[i * TW + j] = acc;
}

// ---------------- block reduce helpers ----------------
__device__ __forceinline__ void blockMaxMinAtomic(float vmax, float vmin,
                                                  unsigned* pmax, unsigned* pmin) {
#pragma unroll
    for (int o = 32; o > 0; o >>= 1) {
        vmax = fmaxf(vmax, __shfl_down(vmax, o));
        vmin = fminf(vmin, __shfl_down(vmin, o));
    }
    __shared__ float smax[4], smin[4];
    int lane = threadIdx.x & 63, wv = threadIdx.x >> 6;
    if (lane == 0) { smax[wv] = vmax; smin[wv] = vmin; }
    __syncthreads();
    if (threadIdx.x == 0) {
        float a = fmaxf(fmaxf(smax[0], smax[1]), fmaxf(smax[2], smax[3]));
        float b = fminf(fminf(smin[0], smin[1]), fminf(smin[2], smin[3]));
        if (pmax) atomicMax(pmax, __float_as_uint(a));
        if (pmin) atomicMin(pmin, __float_as_uint(b));
    }
}

// ---------------- pass 3: sobel + mag + global max ----------------
__global__ void k_sobel(const float* __restrict__ bl, float* __restrict__ mag,
                        unsigned* __restrict__ scal) {
    int j = blockIdx.x * blockDim.x + threadIdx.x;
    float tmax = 0.f;
    for (int i = blockIdx.y; i < TH; i += gridDim.y) {
        float v[3][3];
#pragma unroll
        for (int a = 0; a < 3; a++) {
            int y = i + a - 1;
#pragma unroll
            for (int b = 0; b < 3; b++) {
                int x = j + b - 1;
                v[a][b] = ((unsigned)y < TH && (unsigned)x < TW) ? bl[y * TW + x] : 0.f;
            }
        }
        // cross-correlation, row-major accumulation, no FMA (threshold-sensitive)
        float gx = 0.f;
        gx = __fadd_rn(gx, __fmul_rn(-1.f, v[0][0]));
        gx = __fadd_rn(gx, v[0][2]);
        gx = __fadd_rn(gx, __fmul_rn(-2.f, v[1][0]));
        gx = __fadd_rn(gx, __fmul_rn(2.f, v[1][2]));
        gx = __fadd_rn(gx, __fmul_rn(-1.f, v[2][0]));
        gx = __fadd_rn(gx, v[2][2]);
        float gyv = 0.f;
        gyv = __fadd_rn(gyv, __fmul_rn(-1.f, v[0][0]));
        gyv = __fadd_rn(gyv, __fmul_rn(-2.f, v[0][1]));
        gyv = __fadd_rn(gyv, __fmul_rn(-1.f, v[0][2]));
        gyv = __fadd_rn(gyv, v[2][0]);
        gyv = __fadd_rn(gyv, __fmul_rn(2.f, v[2][1]));
        gyv = __fadd_rn(gyv, v[2][2]);
        float m = sqrtf(__fadd_rn(__fmul_rn(gx, gx), __fmul_rn(gyv, gyv)));
        mag[i * TW + j] = m;
        tmax = fmaxf(tmax, m);
    }
    blockMaxMinAtomic(tmax, 0.f, &scal[0], nullptr);
}

// ---------------- pass 4: histogram scan -> max count, min nonzero count ----------------
__global__ void k_histscan(const unsigned* __restrict__ hist, unsigned* __restrict__ scal) {
    int stride = gridDim.x * blockDim.x;
    unsigned mx = 0u, mn = 0xFFFFFFFFu;
    for (int p = blockIdx.x * blockDim.x + threadIdx.x; p < 32768; p += stride) {
        unsigned c = hist[p];
        mx = max(mx, c);
        if (c > 0u) mn = min(mn, c);
    }
#pragma unroll
    for (int o = 32; o > 0; o >>= 1) {
        mx = max(mx, (unsigned)__shfl_down((int)mx, o));
        mn = min(mn, (unsigned)__shfl_down((int)mn, o));
    }
    __shared__ unsigned smx[4], smn[4];
    int lane = threadIdx.x & 63, wv = threadIdx.x >> 6;
    if (lane == 0) { smx[wv] = mx; smn[wv] = mn; }
    __syncthreads();
    if (threadIdx.x == 0) {
        unsigned a = max(max(smx[0], smx[1]), max(smx[2], smx[3]));
        unsigned b = min(min(smn[0], smn[1]), min(smn[2], smn[3]));
        atomicMax(&scal[3], a);
        atomicMin(&scal[4], b);
    }
}

// ---------------- gauss weights (computed once per block; smooth path) ----------------
__device__ __forceinline__ void gaussWeights(float* wt /*shared[15]*/) {
    if (threadIdx.x == 0) {
        float w[15];
        float s = 0.f;
        for (int t = 0; t < 15; t++) {
            int c = t - 7;
            w[t] = expf(-(float)(c * c) * 0.125f);
            s += w[t];
        }
        for (int t = 0; t < 15; t++) wt[t] = w[t] / s;
    }
    __syncthreads();
}

// ---------------- pass 5: threshold + horizontal 15-tap gauss ----------------
__global__ void k_gaussH(const float* __restrict__ mag, float* __restrict__ tmp,
                         const unsigned* __restrict__ scal) {
    __shared__ float wt[15];
    gaussWeights(wt);
    float magmax = __uint_as_float(scal[0]);
    float hi = __fmul_rn(magmax, 0.2f);
    float lo = __fmul_rn(hi, 0.3f);
    int j = blockIdx.x * blockDim.x + threadIdx.x;
    int i = blockIdx.y;
    const float* row = mag + (size_t)i * TW;
    float acc = 0.f;
#pragma unroll
    for (int t = 0; t < 15; t++) {
        int x = j + t - 7;
        if ((unsigned)x < TW) {
            float m = row[x];
            float e = (m > lo && m < hi) ? 1.f : 0.f;
            acc = fmaf(e, wt[t], acc);
        }
    }
    tmp[(size_t)i * TW + j] = acc;
}

// ---------------- pass 6: vertical 15-tap gauss + ed min/max ----------------
__global__ void k_gaussV(const float* __restrict__ tmp, float* __restrict__ ed,
                         unsigned* __restrict__ scal) {
    __shared__ float wt[15];
    gaussWeights(wt);
    int j = blockIdx.x * blockDim.x + threadIdx.x;
    float tmin = INFINITY, tmax = 0.f;
    for (int i = blockIdx.y; i < TH; i += gridDim.y) {
        float acc = 0.f;
#pragma unroll
        for (int t = 0; t < 15; t++) {
            int y = i + t - 7;
            if ((unsigned)y < TH) acc = fmaf(tmp[(size_t)y * TW + j], wt[t], acc);
        }
        ed[(size_t)i * TW + j] = acc;
        tmin = fminf(tmin, acc);
        tmax = fmaxf(tmax, acc);
    }
    blockMaxMinAtomic(tmax, tmin, &scal[2], &scal[1]);
}

// ---------------- pass 7: normalize + color sparsity + sigmoid ----------------
__global__ void k_final(float* __restrict__ io, const unsigned short* __restrict__ code,
                        const unsigned* __restrict__ hist, const unsigned* __restrict__ scal,
                        const float* __restrict__ alphap, const float* __restrict__ betap) {
    float edmin = __uint_as_float(scal[1]);
    float edmax = __uint_as_float(scal[2]);
    float edrange = edmax - edmin + 1e-9f;
    const float N = (float)NPIX;
    // cs is monotone-decreasing in count -> min/max from histogram extremes
    float csmin = -logf((float)scal[3] / N + 1e-9f) * 1.5f;
    float csmax = -logf((float)scal[4] / N + 1e-9f) * 1.5f;
    float csrange = csmax - csmin + 1e-9f;
    float alpha = *alphap, beta = *betap;
    int stride = gridDim.x * blockDim.x;
    for (int p = blockIdx.x * blockDim.x + threadIdx.x; p < NPIX; p += stride) {
        float ed = io[p];
        float en = (ed - edmin) / edrange;
        float prob = (float)hist[code[p]] / N;
        float cs = -logf(prob + 1e-9f) * 1.5f;
        float cn = (cs - csmin) / csrange;
        float x = alpha * en + beta * cn;
        io[p] = 1.f / (1.f + expf(-x));
    }
}

extern "C" void kernel_launch(void* const* d_in, const int* in_sizes, int n_in,
                              void* d_out, int out_size, void* d_ws, size_t ws_size,
                              hipStream_t stream) {
    const float* img = (const float*)d_in[0];
    const float* alphap = (const float*)d_in[1];
    const float* betap = (const float*)d_in[2];
    float* out = (float*)d_out;

    char* ws = (char*)d_ws;
    unsigned* scal = (unsigned*)ws;                                   // 64 B
    unsigned* hist = (unsigned*)(ws + 1024);                          // 128 KiB
    float* G = (float*)(ws + 262144);                                 // 37.75 MB (gray -> mag)
    float* M = (float*)(ws + 262144 + (size_t)NPIX * 4);              // 37.75 MB (blur -> tmp)
    unsigned short* code = (unsigned short*)(ws + 262144 + (size_t)NPIX * 8);  // 18.9 MB

    hipLaunchKernelGGL(k_init, dim3(1), dim3(64), 0, stream, scal);
    hipMemsetAsync(hist, 0, 32768 * sizeof(unsigned), stream);
    hipLaunchKernelGGL(k_pre, dim3(4608), dim3(256), 0, stream, img, G, code, hist);
    hipLaunchKernelGGL(k_box, dim3(TW / 256, TH), dim3(256), 0, stream, G, M);
    hipLaunchKernelGGL(k_sobel, dim3(TW / 256, 192), dim3(256), 0, stream, M, G, scal);
    hipLaunchKernelGGL(k_histscan, dim3(32), dim3(256), 0, stream, hist, scal);
    hipLaunchKernelGGL(k_gaussH, dim3(TW / 256, TH), dim3(256), 0, stream, G, M, scal);
    hipLaunchKernelGGL(k_gaussV, dim3(TW / 256, 192), dim3(256), 0, stream, M, out, scal);
    hipLaunchKernelGGL(k_final, dim3(4608), dim3(256), 0, stream, out, code, hist, scal,
                       alphap, betap);
}

// Round 2
// 635.477 us; speedup vs baseline: 1.4912x; 1.4912x over previous
//
#include <hip/hip_runtime.h>
#include <math.h>

#define TW 3072
#define TH 3072
#define NPIX (TW*TH)

// scal[0]=magmax bits, scal[1]=edmin bits, scal[2]=edmax bits,
// scal[3]=max hist count, scal[4]=min nonzero hist count
__global__ void k_init(unsigned* scal) {
    if (threadIdx.x == 0) {
        scal[0] = 0u;
        scal[1] = 0x7F800000u;  // +inf
        scal[2] = 0u;
        scal[3] = 0u;
        scal[4] = 0xFFFFFFFFu;
    }
}

__device__ __forceinline__ int qcode(float r, float g, float b) {
    int ir = min(max((int)rintf(__fmul_rn(r, 31.f)), 0), 31);
    int ig = min(max((int)rintf(__fmul_rn(g, 31.f)), 0), 31);
    int ib = min(max((int)rintf(__fmul_rn(b, 31.f)), 0), 31);
    return ir * 1024 + ig * 32 + ib;
}

__device__ __forceinline__ float grayf(float r, float g, float b) {
    // no FMA contraction: threshold-sensitive path must match numpy bit-closely
    return __fadd_rn(__fadd_rn(__fmul_rn(0.299f, r), __fmul_rn(0.587f, g)),
                     __fmul_rn(0.114f, b));
}

// ---------------- pass 1: gray + code + per-block LDS histogram ----------------
// 512 blocks x 512 threads; <=18432 px/block so per-bin block counts fit u16.
// 32768 bins packed 2-per-u32 in 64 KB LDS; flushed with plain stores.
__global__ __launch_bounds__(512) void k_pre(const float4* __restrict__ img4,
                                             float4* __restrict__ gray4,
                                             ushort4* __restrict__ code4,
                                             unsigned* __restrict__ parthist) {
    __shared__ unsigned lh[16384];  // 64 KB: bins 2b (lo16) / 2b+1 (hi16)
    for (int t = threadIdx.x; t < 16384; t += 512) lh[t] = 0u;
    __syncthreads();
    const int total4 = NPIX / 4;
    int stride = gridDim.x * blockDim.x;
    for (int p = blockIdx.x * blockDim.x + threadIdx.x; p < total4; p += stride) {
        float4 r = img4[p], g = img4[p + total4], b = img4[p + 2 * total4];
        float4 gy;
        gy.x = grayf(r.x, g.x, b.x);
        gy.y = grayf(r.y, g.y, b.y);
        gy.z = grayf(r.z, g.z, b.z);
        gy.w = grayf(r.w, g.w, b.w);
        gray4[p] = gy;
        int c0 = qcode(r.x, g.x, b.x);
        int c1 = qcode(r.y, g.y, b.y);
        int c2 = qcode(r.z, g.z, b.z);
        int c3 = qcode(r.w, g.w, b.w);
        atomicAdd(&lh[c0 >> 1], (c0 & 1) ? 0x10000u : 1u);
        atomicAdd(&lh[c1 >> 1], (c1 & 1) ? 0x10000u : 1u);
        atomicAdd(&lh[c2 >> 1], (c2 & 1) ? 0x10000u : 1u);
        atomicAdd(&lh[c3 >> 1], (c3 & 1) ? 0x10000u : 1u);
        ushort4 cc;
        cc.x = (unsigned short)c0; cc.y = (unsigned short)c1;
        cc.z = (unsigned short)c2; cc.w = (unsigned short)c3;
        code4[p] = cc;
    }
    __syncthreads();
    unsigned* dst = parthist + (size_t)blockIdx.x * 16384;
    for (int t = threadIdx.x; t < 16384; t += 512) dst[t] = lh[t];
}

// ---------------- pass 2: reduce partials -> hist + max/min-nonzero ----------------
__global__ void k_reduce(const unsigned* __restrict__ parthist, unsigned* __restrict__ hist,
                         unsigned* __restrict__ scal) {
    int b = blockIdx.x * blockDim.x + threadIdx.x;  // 0..16383 (bin pair)
    unsigned lo = 0u, hi = 0u;
    for (int k = 0; k < 512; k++) {
        unsigned v = parthist[(size_t)k * 16384 + b];
        lo += v & 0xFFFFu;
        hi += v >> 16;
    }
    hist[2 * b] = lo;
    hist[2 * b + 1] = hi;
    unsigned mx = max(lo, hi);
    unsigned mn = 0xFFFFFFFFu;
    if (lo) mn = lo;
    if (hi) mn = min(mn, hi);
#pragma unroll
    for (int o = 32; o > 0; o >>= 1) {
        mx = max(mx, (unsigned)__shfl_down((int)mx, o));
        mn = min(mn, (unsigned)__shfl_down((int)mn, o));
    }
    __shared__ unsigned smx[4], smn[4];
    int lane = threadIdx.x & 63, wv = threadIdx.x >> 6;
    if (lane == 0) { smx[wv] = mx; smn[wv] = mn; }
    __syncthreads();
    if (threadIdx.x == 0) {
        unsigned a = max(max(smx[0], smx[1]), max(smx[2], smx[3]));
        unsigned c = min(min(smn[0], smn[1]), min(smn[2], smn[3]));
        atomicMax(&scal[3], a);
        atomicMin(&scal[4], c);
    }
}

// ---------------- pass 3: 5x5 box blur (zero pad, /25 everywhere) ----------------
__global__ void k_box(const float* __restrict__ g, float* __restrict__ out) {
    int j = blockIdx.x * blockDim.x + threadIdx.x;
    int i = blockIdx.y;
    float acc = 0.f;
#pragma unroll
    for (int a = -2; a <= 2; a++) {
        int y = i + a;
        if ((unsigned)y >= TH) continue;
#pragma unroll
        for (int b = -2; b <= 2; b++) {
            int x = j + b;
            if ((unsigned)x >= TW) continue;
            acc = __fadd_rn(acc, __fmul_rn(g[y * TW + x], 0.04f));
        }
    }
    out[i * TW + j] = acc;
}

__device__ __forceinline__ void blockMaxMinAtomic(float vmax, float vmin,
                                                  unsigned* pmax, unsigned* pmin) {
#pragma unroll
    for (int o = 32; o > 0; o >>= 1) {
        vmax = fmaxf(vmax, __shfl_down(vmax, o));
        vmin = fminf(vmin, __shfl_down(vmin, o));
    }
    __shared__ float smax[4], smin[4];
    int lane = threadIdx.x & 63, wv = threadIdx.x >> 6;
    if (lane == 0) { smax[wv] = vmax; smin[wv] = vmin; }
    __syncthreads();
    if (threadIdx.x == 0) {
        float a = fmaxf(fmaxf(smax[0], smax[1]), fmaxf(smax[2], smax[3]));
        float b = fminf(fminf(smin[0], smin[1]), fminf(smin[2], smin[3]));
        if (pmax) atomicMax(pmax, __float_as_uint(a));
        if (pmin) atomicMin(pmin, __float_as_uint(b));
    }
}

// ---------------- pass 4: sobel + mag + global max (16 contiguous rows/block) ----------------
__global__ void k_sobel(const float* __restrict__ bl, float* __restrict__ mag,
                        unsigned* __restrict__ scal) {
    int j = blockIdx.x * blockDim.x + threadIdx.x;
    int i0 = blockIdx.y * 16;
    float tmax = 0.f;
    for (int i = i0; i < i0 + 16; i++) {
        float v[3][3];
#pragma unroll
        for (int a = 0; a < 3; a++) {
            int y = i + a - 1;
#pragma unroll
            for (int b = 0; b < 3; b++) {
                int x = j + b - 1;
                v[a][b] = ((unsigned)y < TH && (unsigned)x < TW) ? bl[y * TW + x] : 0.f;
            }
        }
        float gx = 0.f;
        gx = __fadd_rn(gx, __fmul_rn(-1.f, v[0][0]));
        gx = __fadd_rn(gx, v[0][2]);
        gx = __fadd_rn(gx, __fmul_rn(-2.f, v[1][0]));
        gx = __fadd_rn(gx, __fmul_rn(2.f, v[1][2]));
        gx = __fadd_rn(gx, __fmul_rn(-1.f, v[2][0]));
        gx = __fadd_rn(gx, v[2][2]);
        float gyv = 0.f;
        gyv = __fadd_rn(gyv, __fmul_rn(-1.f, v[0][0]));
        gyv = __fadd_rn(gyv, __fmul_rn(-2.f, v[0][1]));
        gyv = __fadd_rn(gyv, __fmul_rn(-1.f, v[0][2]));
        gyv = __fadd_rn(gyv, v[2][0]);
        gyv = __fadd_rn(gyv, __fmul_rn(2.f, v[2][1]));
        gyv = __fadd_rn(gyv, v[2][2]);
        float m = sqrtf(__fadd_rn(__fmul_rn(gx, gx), __fmul_rn(gyv, gyv)));
        mag[(size_t)i * TW + j] = m;
        tmax = fmaxf(tmax, m);
    }
    blockMaxMinAtomic(tmax, 0.f, &scal[0], nullptr);
}

// ---------------- gauss weights (once per block; smooth path) ----------------
__device__ __forceinline__ void gaussWeights(float* wt) {
    if (threadIdx.x == 0) {
        float w[15];
        float s = 0.f;
        for (int t = 0; t < 15; t++) {
            int c = t - 7;
            w[t] = expf(-(float)(c * c) * 0.125f);
            s += w[t];
        }
        for (int t = 0; t < 15; t++) wt[t] = w[t] / s;
    }
    __syncthreads();
}

// ---------------- pass 5: threshold + horizontal 15-tap gauss ----------------
__global__ void k_gaussH(const float* __restrict__ mag, float* __restrict__ tmp,
                         const unsigned* __restrict__ scal) {
    __shared__ float wt[15];
    gaussWeights(wt);
    float magmax = __uint_as_float(scal[0]);
    float hi = __fmul_rn(magmax, 0.2f);
    float lo = __fmul_rn(hi, 0.3f);
    int j = blockIdx.x * blockDim.x + threadIdx.x;
    int i = blockIdx.y;
    const float* row = mag + (size_t)i * TW;
    float acc = 0.f;
#pragma unroll
    for (int t = 0; t < 15; t++) {
        int x = j + t - 7;
        if ((unsigned)x < TW) {
            float m = row[x];
            float e = (m > lo && m < hi) ? 1.f : 0.f;
            acc = fmaf(e, wt[t], acc);
        }
    }
    tmp[(size_t)i * TW + j] = acc;
}

// ---------------- pass 6: vertical 15-tap gauss + ed min/max (16 rows/block) ----------------
__global__ void k_gaussV(const float* __restrict__ tmp, float* __restrict__ ed,
                         unsigned* __restrict__ scal) {
    __shared__ float wt[15];
    gaussWeights(wt);
    int j = blockIdx.x * blockDim.x + threadIdx.x;
    int i0 = blockIdx.y * 16;
    float tmin = INFINITY, tmax = 0.f;
    for (int i = i0; i < i0 + 16; i++) {
        float acc = 0.f;
#pragma unroll
        for (int t = 0; t < 15; t++) {
            int y = i + t - 7;
            if ((unsigned)y < TH) acc = fmaf(tmp[(size_t)y * TW + j], wt[t], acc);
        }
        ed[(size_t)i * TW + j] = acc;
        tmin = fminf(tmin, acc);
        tmax = fmaxf(tmax, acc);
    }
    blockMaxMinAtomic(tmax, tmin, &scal[2], &scal[1]);
}

// ---------------- pass 7: normalize + color sparsity + sigmoid ----------------
__global__ void k_final(float* __restrict__ io, const unsigned short* __restrict__ code,
                        const unsigned* __restrict__ hist, const unsigned* __restrict__ scal,
                        const float* __restrict__ alphap, const float* __restrict__ betap) {
    float edmin = __uint_as_float(scal[1]);
    float edmax = __uint_as_float(scal[2]);
    float edrange = edmax - edmin + 1e-9f;
    const float N = (float)NPIX;
    float csmin = -logf((float)scal[3] / N + 1e-9f) * 1.5f;
    float csmax = -logf((float)scal[4] / N + 1e-9f) * 1.5f;
    float csrange = csmax - csmin + 1e-9f;
    float alpha = *alphap, beta = *betap;
    int stride = gridDim.x * blockDim.x;
    for (int p = blockIdx.x * blockDim.x + threadIdx.x; p < NPIX; p += stride) {
        float ed = io[p];
        float en = (ed - edmin) / edrange;
        float prob = (float)hist[code[p]] / N;
        float cs = -logf(prob + 1e-9f) * 1.5f;
        float cn = (cs - csmin) / csrange;
        float x = alpha * en + beta * cn;
        io[p] = 1.f / (1.f + expf(-x));
    }
}

extern "C" void kernel_launch(void* const* d_in, const int* in_sizes, int n_in,
                              void* d_out, int out_size, void* d_ws, size_t ws_size,
                              hipStream_t stream) {
    const float* img = (const float*)d_in[0];
    const float* alphap = (const float*)d_in[1];
    const float* betap = (const float*)d_in[2];
    float* out = (float*)d_out;

    char* ws = (char*)d_ws;
    unsigned* scal = (unsigned*)ws;                                   // 64 B
    unsigned* hist = (unsigned*)(ws + 1024);                          // 128 KiB
    float* G = (float*)(ws + 262144);                                 // 37.75 MB (gray -> mag)
    float* M = (float*)(ws + 262144 + (size_t)NPIX * 4);              // 37.75 MB (blur -> tmp)
    unsigned short* code = (unsigned short*)(ws + 262144 + (size_t)NPIX * 8);  // 18.9 MB
    // parthist (512 x 16384 u32 = 32 MB) aliases M: dead before k_box writes M
    unsigned* parthist = (unsigned*)M;

    hipLaunchKernelGGL(k_init, dim3(1), dim3(64), 0, stream, scal);
    hipLaunchKernelGGL(k_pre, dim3(512), dim3(512), 0, stream,
                       (const float4*)img, (float4*)G, (ushort4*)code, parthist);
    hipLaunchKernelGGL(k_reduce, dim3(64), dim3(256), 0, stream, parthist, hist, scal);
    hipLaunchKernelGGL(k_box, dim3(TW / 256, TH), dim3(256), 0, stream, G, M);
    hipLaunchKernelGGL(k_sobel, dim3(TW / 256, TH / 16), dim3(256), 0, stream, M, G, scal);
    hipLaunchKernelGGL(k_gaussH, dim3(TW / 256, TH), dim3(256), 0, stream, G, M, scal);
    hipLaunchKernelGGL(k_gaussV, dim3(TW / 256, TH / 16), dim3(256), 0, stream, M, out, scal);
    hipLaunchKernelGGL(k_final, dim3(4608), dim3(256), 0, stream, out, code, hist, scal,
                       alphap, betap);
}

// Round 3
// 420.922 us; speedup vs baseline: 2.2513x; 1.5097x over previous
//
#include <hip/hip_runtime.h>
#include <math.h>

#define TW 3072
#define TH 3072
#define NPIX (TW*TH)

// scal[0]=magmax bits, scal[1]=edmin bits, scal[2]=edmax bits,
// scal[3]=max hist count, scal[4]=min nonzero hist count
__global__ void k_init(unsigned* scal) {
    if (threadIdx.x == 0) {
        scal[0] = 0u;
        scal[1] = 0x7F800000u;  // +inf
        scal[2] = 0u;
        scal[3] = 0u;
        scal[4] = 0xFFFFFFFFu;
    }
}

__device__ __forceinline__ int qcode(float r, float g, float b) {
    int ir = min(max((int)rintf(__fmul_rn(r, 31.f)), 0), 31);
    int ig = min(max((int)rintf(__fmul_rn(g, 31.f)), 0), 31);
    int ib = min(max((int)rintf(__fmul_rn(b, 31.f)), 0), 31);
    return ir * 1024 + ig * 32 + ib;
}

__device__ __forceinline__ float grayf(float r, float g, float b) {
    // no FMA contraction: threshold-sensitive path must match numpy bit-closely
    return __fadd_rn(__fadd_rn(__fmul_rn(0.299f, r), __fmul_rn(0.587f, g)),
                     __fmul_rn(0.114f, b));
}

// ---------------- pass 1: gray + code + per-block LDS histogram ----------------
__global__ __launch_bounds__(512) void k_pre(const float4* __restrict__ img4,
                                             float4* __restrict__ gray4,
                                             ushort4* __restrict__ code4,
                                             unsigned* __restrict__ parthist) {
    __shared__ unsigned lh[16384];  // 64 KB: bins 2b (lo16) / 2b+1 (hi16)
    for (int t = threadIdx.x; t < 16384; t += 512) lh[t] = 0u;
    __syncthreads();
    const int total4 = NPIX / 4;
    int stride = gridDim.x * blockDim.x;
    for (int p = blockIdx.x * blockDim.x + threadIdx.x; p < total4; p += stride) {
        float4 r = img4[p], g = img4[p + total4], b = img4[p + 2 * total4];
        float4 gy;
        gy.x = grayf(r.x, g.x, b.x);
        gy.y = grayf(r.y, g.y, b.y);
        gy.z = grayf(r.z, g.z, b.z);
        gy.w = grayf(r.w, g.w, b.w);
        gray4[p] = gy;
        int c0 = qcode(r.x, g.x, b.x);
        int c1 = qcode(r.y, g.y, b.y);
        int c2 = qcode(r.z, g.z, b.z);
        int c3 = qcode(r.w, g.w, b.w);
        atomicAdd(&lh[c0 >> 1], (c0 & 1) ? 0x10000u : 1u);
        atomicAdd(&lh[c1 >> 1], (c1 & 1) ? 0x10000u : 1u);
        atomicAdd(&lh[c2 >> 1], (c2 & 1) ? 0x10000u : 1u);
        atomicAdd(&lh[c3 >> 1], (c3 & 1) ? 0x10000u : 1u);
        ushort4 cc;
        cc.x = (unsigned short)c0; cc.y = (unsigned short)c1;
        cc.z = (unsigned short)c2; cc.w = (unsigned short)c3;
        code4[p] = cc;
    }
    __syncthreads();
    unsigned* dst = parthist + (size_t)blockIdx.x * 16384;
    for (int t = threadIdx.x; t < 16384; t += 512) dst[t] = lh[t];
}

// ---------------- pass 2: reduce partials -> hist + max/min-nonzero ----------------
__global__ void k_reduce(const unsigned* __restrict__ parthist, unsigned* __restrict__ hist,
                         unsigned* __restrict__ scal) {
    int b = blockIdx.x * blockDim.x + threadIdx.x;  // 0..16383 (bin pair)
    unsigned lo = 0u, hi = 0u;
    for (int k = 0; k < 512; k++) {
        unsigned v = parthist[(size_t)k * 16384 + b];
        lo += v & 0xFFFFu;
        hi += v >> 16;
    }
    hist[2 * b] = lo;
    hist[2 * b + 1] = hi;
    unsigned mx = max(lo, hi);
    unsigned mn = 0xFFFFFFFFu;
    if (lo) mn = lo;
    if (hi) mn = min(mn, hi);
#pragma unroll
    for (int o = 32; o > 0; o >>= 1) {
        mx = max(mx, (unsigned)__shfl_down((int)mx, o));
        mn = min(mn, (unsigned)__shfl_down((int)mn, o));
    }
    __shared__ unsigned smx[4], smn[4];
    int lane = threadIdx.x & 63, wv = threadIdx.x >> 6;
    if (lane == 0) { smx[wv] = mx; smn[wv] = mn; }
    __syncthreads();
    if (threadIdx.x == 0) {
        unsigned a = max(max(smx[0], smx[1]), max(smx[2], smx[3]));
        unsigned c = min(min(smn[0], smn[1]), min(smn[2], smn[3]));
        atomicMax(&scal[3], a);
        atomicMin(&scal[4], c);
    }
}

// ---------------- pass 3: 5x5 box blur, vertical register ring, 16 rows/thread ----------------
__global__ void k_box(const float* __restrict__ g, float* __restrict__ out) {
    int j = blockIdx.x * blockDim.x + threadIdx.x;
    int i0 = blockIdx.y * 16;
    float ring[5][5];  // ring[(y-(i0-2))%5][b] = taps g[y][j-2+b]
#pragma unroll
    for (int s = 0; s < 4; s++) {  // preload rows i0-2 .. i0+1
        int y = i0 - 2 + s;
#pragma unroll
        for (int b = 0; b < 5; b++) {
            int x = j - 2 + b;
            ring[s][b] = ((unsigned)y < TH && (unsigned)x < TW) ? g[(size_t)y * TW + x] : 0.f;
        }
    }
#pragma unroll
    for (int r = 0; r < 16; r++) {
        int y = i0 + r + 2;
        int sNew = (r + 4) % 5;
#pragma unroll
        for (int b = 0; b < 5; b++) {
            int x = j - 2 + b;
            ring[sNew][b] = ((unsigned)y < TH && (unsigned)x < TW) ? g[(size_t)y * TW + x] : 0.f;
        }
        float acc = 0.f;
#pragma unroll
        for (int a = 0; a < 5; a++) {  // same row-major term order as round 2
            int s = (r + a) % 5;
#pragma unroll
            for (int b = 0; b < 5; b++)
                acc = __fadd_rn(acc, __fmul_rn(ring[s][b], 0.04f));
        }
        out[(size_t)(i0 + r) * TW + j] = acc;
    }
}

__device__ __forceinline__ void blockMaxMinAtomic(float vmax, float vmin,
                                                  unsigned* pmax, unsigned* pmin) {
#pragma unroll
    for (int o = 32; o > 0; o >>= 1) {
        vmax = fmaxf(vmax, __shfl_down(vmax, o));
        vmin = fminf(vmin, __shfl_down(vmin, o));
    }
    __shared__ float smax[4], smin[4];
    int lane = threadIdx.x & 63, wv = threadIdx.x >> 6;
    if (lane == 0) { smax[wv] = vmax; smin[wv] = vmin; }
    __syncthreads();
    if (threadIdx.x == 0) {
        float a = fmaxf(fmaxf(smax[0], smax[1]), fmaxf(smax[2], smax[3]));
        float b = fminf(fminf(smin[0], smin[1]), fminf(smin[2], smin[3]));
        if (pmax) atomicMax(pmax, __float_as_uint(a));
        if (pmin) atomicMin(pmin, __float_as_uint(b));
    }
}

// ---------------- pass 4: sobel + mag + max, vertical register ring, 16 rows/thread ----------------
__global__ void k_sobel(const float* __restrict__ bl, float* __restrict__ mag,
                        unsigned* __restrict__ scal) {
    int j = blockIdx.x * blockDim.x + threadIdx.x;
    int i0 = blockIdx.y * 16;
    float ring[3][3];  // ring[(y-(i0-1))%3][b] = bl[y][j-1+b]
#pragma unroll
    for (int s = 0; s < 2; s++) {  // preload rows i0-1, i0
        int y = i0 - 1 + s;
#pragma unroll
        for (int b = 0; b < 3; b++) {
            int x = j - 1 + b;
            ring[s][b] = ((unsigned)y < TH && (unsigned)x < TW) ? bl[(size_t)y * TW + x] : 0.f;
        }
    }
    float tmax = 0.f;
#pragma unroll
    for (int r = 0; r < 16; r++) {
        int y = i0 + r + 1;
        int sNew = (r + 2) % 3;
#pragma unroll
        for (int b = 0; b < 3; b++) {
            int x = j - 1 + b;
            ring[sNew][b] = ((unsigned)y < TH && (unsigned)x < TW) ? bl[(size_t)y * TW + x] : 0.f;
        }
        float v[3][3];
#pragma unroll
        for (int a = 0; a < 3; a++) {
            int s = (r + a) % 3;
#pragma unroll
            for (int b = 0; b < 3; b++) v[a][b] = ring[s][b];
        }
        float gx = 0.f;
        gx = __fadd_rn(gx, __fmul_rn(-1.f, v[0][0]));
        gx = __fadd_rn(gx, v[0][2]);
        gx = __fadd_rn(gx, __fmul_rn(-2.f, v[1][0]));
        gx = __fadd_rn(gx, __fmul_rn(2.f, v[1][2]));
        gx = __fadd_rn(gx, __fmul_rn(-1.f, v[2][0]));
        gx = __fadd_rn(gx, v[2][2]);
        float gyv = 0.f;
        gyv = __fadd_rn(gyv, __fmul_rn(-1.f, v[0][0]));
        gyv = __fadd_rn(gyv, __fmul_rn(-2.f, v[0][1]));
        gyv = __fadd_rn(gyv, __fmul_rn(-1.f, v[0][2]));
        gyv = __fadd_rn(gyv, v[2][0]);
        gyv = __fadd_rn(gyv, __fmul_rn(2.f, v[2][1]));
        gyv = __fadd_rn(gyv, v[2][2]);
        float m = sqrtf(__fadd_rn(__fmul_rn(gx, gx), __fmul_rn(gyv, gyv)));
        mag[(size_t)(i0 + r) * TW + j] = m;
        tmax = fmaxf(tmax, m);
    }
    blockMaxMinAtomic(tmax, 0.f, &scal[0], nullptr);
}

// ---------------- gauss weights (once per block; smooth path) ----------------
__device__ __forceinline__ void gaussWeights(float* wt) {
    if (threadIdx.x == 0) {
        float w[15];
        float s = 0.f;
        for (int t = 0; t < 15; t++) {
            int c = t - 7;
            w[t] = expf(-(float)(c * c) * 0.125f);
            s += w[t];
        }
        for (int t = 0; t < 15; t++) wt[t] = w[t] / s;
    }
    __syncthreads();
}

// ---------------- pass 5: threshold + horizontal 15-tap gauss via LDS row ----------------
__global__ void k_gaussH(const float* __restrict__ mag, float* __restrict__ tmp,
                         const unsigned* __restrict__ scal) {
    __shared__ float wt[15];
    __shared__ float e[272];
    gaussWeights(wt);
    float magmax = __uint_as_float(scal[0]);
    float hi = __fmul_rn(magmax, 0.2f);
    float lo = __fmul_rn(hi, 0.3f);
    int i = blockIdx.y;
    int j0 = blockIdx.x * 256;
    const float* row = mag + (size_t)i * TW;
    for (int t = threadIdx.x; t < 270; t += 256) {
        int x = j0 - 7 + t;
        float m = ((unsigned)x < TW) ? row[x] : 0.f;  // OOB -> e=0, bit-same as skipping
        e[t] = (m > lo && m < hi) ? 1.f : 0.f;
    }
    __syncthreads();
    float acc = 0.f;
#pragma unroll
    for (int t = 0; t < 15; t++) acc = fmaf(e[threadIdx.x + t], wt[t], acc);
    tmp[(size_t)i * TW + j0 + threadIdx.x] = acc;
}

// ---------------- pass 6: vertical 15-tap gauss via LDS tile + ed min/max ----------------
__global__ __launch_bounds__(256) void k_gaussV(const float* __restrict__ tmp,
                                                float* __restrict__ ed,
                                                unsigned* __restrict__ scal) {
    __shared__ float wt[15];
    __shared__ float S[46 * 256];  // 46 rows x 256 cols = 47 KB
    gaussWeights(wt);
    int tx = threadIdx.x;
    int j = blockIdx.x * 256 + tx;
    int y0 = blockIdx.y * 32;
#pragma unroll
    for (int s = 0; s < 46; s++) {
        int y = y0 - 7 + s;
        S[s * 256 + tx] = ((unsigned)y < TH) ? tmp[(size_t)y * TW + j] : 0.f;
    }
    __syncthreads();
    float tmin = INFINITY, tmax = 0.f;
#pragma unroll 4
    for (int r = 0; r < 32; r++) {
        float acc = 0.f;
#pragma unroll
        for (int t = 0; t < 15; t++) acc = fmaf(S[(r + t) * 256 + tx], wt[t], acc);
        ed[(size_t)(y0 + r) * TW + j] = acc;
        tmin = fminf(tmin, acc);
        tmax = fmaxf(tmax, acc);
    }
    blockMaxMinAtomic(tmax, tmin, &scal[2], &scal[1]);
}

// ---------------- pass 7: normalize + color sparsity + sigmoid (vectorized) ----------------
__global__ void k_final(float4* __restrict__ io4, const ushort4* __restrict__ code4,
                        const unsigned* __restrict__ hist, const unsigned* __restrict__ scal,
                        const float* __restrict__ alphap, const float* __restrict__ betap) {
    float edmin = __uint_as_float(scal[1]);
    float edmax = __uint_as_float(scal[2]);
    float edrange = edmax - edmin + 1e-9f;
    const float N = (float)NPIX;
    float csmin = -logf((float)scal[3] / N + 1e-9f) * 1.5f;
    float csmax = -logf((float)scal[4] / N + 1e-9f) * 1.5f;
    float csrange = csmax - csmin + 1e-9f;
    float alpha = *alphap, beta = *betap;
    const int total4 = NPIX / 4;
    int stride = gridDim.x * blockDim.x;
    for (int p = blockIdx.x * blockDim.x + threadIdx.x; p < total4; p += stride) {
        float4 ed = io4[p];
        ushort4 cc = code4[p];
        float edv[4] = {ed.x, ed.y, ed.z, ed.w};
        unsigned short cv[4] = {cc.x, cc.y, cc.z, cc.w};
        float ov[4];
#pragma unroll
        for (int t = 0; t < 4; t++) {
            float en = (edv[t] - edmin) / edrange;
            float prob = (float)hist[cv[t]] / N;
            float cs = -logf(prob + 1e-9f) * 1.5f;
            float cn = (cs - csmin) / csrange;
            float x = alpha * en + beta * cn;
            ov[t] = 1.f / (1.f + expf(-x));
        }
        float4 o;
        o.x = ov[0]; o.y = ov[1]; o.z = ov[2]; o.w = ov[3];
        io4[p] = o;
    }
}

extern "C" void kernel_launch(void* const* d_in, const int* in_sizes, int n_in,
                              void* d_out, int out_size, void* d_ws, size_t ws_size,
                              hipStream_t stream) {
    const float* img = (const float*)d_in[0];
    const float* alphap = (const float*)d_in[1];
    const float* betap = (const float*)d_in[2];
    float* out = (float*)d_out;

    char* ws = (char*)d_ws;
    unsigned* scal = (unsigned*)ws;                                   // 64 B
    unsigned* hist = (unsigned*)(ws + 1024);                          // 128 KiB
    float* G = (float*)(ws + 262144);                                 // 37.75 MB (gray -> mag)
    float* M = (float*)(ws + 262144 + (size_t)NPIX * 4);              // 37.75 MB (blur -> tmp)
    unsigned short* code = (unsigned short*)(ws + 262144 + (size_t)NPIX * 8);  // 18.9 MB
    // parthist (512 x 16384 u32 = 32 MB) aliases M: dead before k_box writes M
    unsigned* parthist = (unsigned*)M;

    hipLaunchKernelGGL(k_init, dim3(1), dim3(64), 0, stream, scal);
    hipLaunchKernelGGL(k_pre, dim3(512), dim3(512), 0, stream,
                       (const float4*)img, (float4*)G, (ushort4*)code, parthist);
    hipLaunchKernelGGL(k_reduce, dim3(64), dim3(256), 0, stream, parthist, hist, scal);
    hipLaunchKernelGGL(k_box, dim3(TW / 256, TH / 16), dim3(256), 0, stream, G, M);
    hipLaunchKernelGGL(k_sobel, dim3(TW / 256, TH / 16), dim3(256), 0, stream, M, G, scal);
    hipLaunchKernelGGL(k_gaussH, dim3(TW / 256, TH), dim3(256), 0, stream, G, M, scal);
    hipLaunchKernelGGL(k_gaussV, dim3(TW / 256, TH / 32), dim3(256), 0, stream, M, out, scal);
    hipLaunchKernelGGL(k_final, dim3(2304), dim3(256), 0, stream, (float4*)out,
                       (const ushort4*)code, hist, scal, alphap, betap);
}

// Round 4
// 375.177 us; speedup vs baseline: 2.5258x; 1.1219x over previous
//
#include <hip/hip_runtime.h>
#include <math.h>

#define TW 3072
#define TH 3072
#define NPIX (TW*TH)

// scal[0]=magmax bits, scal[1]=edmin bits, scal[2]=edmax bits,
// scal[3]=max hist count, scal[4]=min nonzero hist count
__global__ void k_init(unsigned* scal) {
    if (threadIdx.x == 0) {
        scal[0] = 0u;
        scal[1] = 0x7F800000u;  // +inf
        scal[2] = 0u;
        scal[3] = 0u;
        scal[4] = 0xFFFFFFFFu;
    }
}

__device__ __forceinline__ int qcode(float r, float g, float b) {
    int ir = min(max((int)rintf(__fmul_rn(r, 31.f)), 0), 31);
    int ig = min(max((int)rintf(__fmul_rn(g, 31.f)), 0), 31);
    int ib = min(max((int)rintf(__fmul_rn(b, 31.f)), 0), 31);
    return ir * 1024 + ig * 32 + ib;
}

__device__ __forceinline__ float grayf(float r, float g, float b) {
    // no FMA contraction: threshold-sensitive path must match numpy bit-closely
    return __fadd_rn(__fadd_rn(__fmul_rn(0.299f, r), __fmul_rn(0.587f, g)),
                     __fmul_rn(0.114f, b));
}

// ---------------- pass 1: gray + code + per-block LDS histogram ----------------
__global__ __launch_bounds__(512) void k_pre(const float4* __restrict__ img4,
                                             float4* __restrict__ gray4,
                                             ushort4* __restrict__ code4,
                                             unsigned* __restrict__ parthist) {
    __shared__ unsigned lh[16384];  // 64 KB: bins 2b (lo16) / 2b+1 (hi16)
    for (int t = threadIdx.x; t < 16384; t += 512) lh[t] = 0u;
    __syncthreads();
    const int total4 = NPIX / 4;
    int stride = gridDim.x * blockDim.x;
    for (int p = blockIdx.x * blockDim.x + threadIdx.x; p < total4; p += stride) {
        float4 r = img4[p], g = img4[p + total4], b = img4[p + 2 * total4];
        float4 gy;
        gy.x = grayf(r.x, g.x, b.x);
        gy.y = grayf(r.y, g.y, b.y);
        gy.z = grayf(r.z, g.z, b.z);
        gy.w = grayf(r.w, g.w, b.w);
        gray4[p] = gy;
        int c0 = qcode(r.x, g.x, b.x);
        int c1 = qcode(r.y, g.y, b.y);
        int c2 = qcode(r.z, g.z, b.z);
        int c3 = qcode(r.w, g.w, b.w);
        atomicAdd(&lh[c0 >> 1], (c0 & 1) ? 0x10000u : 1u);
        atomicAdd(&lh[c1 >> 1], (c1 & 1) ? 0x10000u : 1u);
        atomicAdd(&lh[c2 >> 1], (c2 & 1) ? 0x10000u : 1u);
        atomicAdd(&lh[c3 >> 1], (c3 & 1) ? 0x10000u : 1u);
        ushort4 cc;
        cc.x = (unsigned short)c0; cc.y = (unsigned short)c1;
        cc.z = (unsigned short)c2; cc.w = (unsigned short)c3;
        code4[p] = cc;
    }
    __syncthreads();
    unsigned* dst = parthist + (size_t)blockIdx.x * 16384;
    for (int t = threadIdx.x; t < 16384; t += 512) dst[t] = lh[t];
}

// ---------------- pass 2: reduce partials -> hist + max/min-nonzero ----------------
__global__ void k_reduce(const unsigned* __restrict__ parthist, unsigned* __restrict__ hist,
                         unsigned* __restrict__ scal) {
    int b = blockIdx.x * blockDim.x + threadIdx.x;  // 0..16383 (bin pair)
    unsigned lo = 0u, hi = 0u;
#pragma unroll 4
    for (int k = 0; k < 512; k++) {
        unsigned v = parthist[(size_t)k * 16384 + b];
        lo += v & 0xFFFFu;
        hi += v >> 16;
    }
    hist[2 * b] = lo;
    hist[2 * b + 1] = hi;
    unsigned mx = max(lo, hi);
    unsigned mn = 0xFFFFFFFFu;
    if (lo) mn = lo;
    if (hi) mn = min(mn, hi);
#pragma unroll
    for (int o = 32; o > 0; o >>= 1) {
        mx = max(mx, (unsigned)__shfl_down((int)mx, o));
        mn = min(mn, (unsigned)__shfl_down((int)mn, o));
    }
    __shared__ unsigned smx[4], smn[4];
    int lane = threadIdx.x & 63, wv = threadIdx.x >> 6;
    if (lane == 0) { smx[wv] = mx; smn[wv] = mn; }
    __syncthreads();
    if (threadIdx.x == 0) {
        unsigned a = max(max(smx[0], smx[1]), max(smx[2], smx[3]));
        unsigned c = min(min(smn[0], smn[1]), min(smn[2], smn[3]));
        atomicMax(&scal[3], a);
        atomicMin(&scal[4], c);
    }
}

// generic block max/min -> global atomics (supports 256 or 512 threads)
__device__ __forceinline__ void blockMaxMinAtomic(float vmax, float vmin,
                                                  unsigned* pmax, unsigned* pmin) {
#pragma unroll
    for (int o = 32; o > 0; o >>= 1) {
        vmax = fmaxf(vmax, __shfl_down(vmax, o));
        vmin = fminf(vmin, __shfl_down(vmin, o));
    }
    __shared__ float smax[8], smin[8];
    int lane = threadIdx.x & 63, wv = threadIdx.x >> 6;
    if (lane == 0) { smax[wv] = vmax; smin[wv] = vmin; }
    __syncthreads();
    if (threadIdx.x == 0) {
        int nw = blockDim.x >> 6;
        float a = smax[0], b = smin[0];
        for (int k = 1; k < nw; k++) { a = fmaxf(a, smax[k]); b = fminf(b, smin[k]); }
        if (pmax) atomicMax(pmax, __float_as_uint(a));
        if (pmin) atomicMin(pmin, __float_as_uint(b));
    }
}

// ---------------- pass 3: fused 5x5 box + sobel + mag + magmax ----------------
// tile: 256 cols x 24 out rows. GT = gray + halo(3), BL = blurred + halo(1).
#define BS_W 256
#define BS_H 24
#define GT_W 262
#define GT_H 30
#define BL_W 258
#define BL_H 26
__global__ __launch_bounds__(512) void k_boxsobel(const float* __restrict__ g,
                                                  float* __restrict__ mag,
                                                  unsigned* __restrict__ scal) {
    __shared__ float GT[GT_H * GT_W];  // 31.4 KB
    __shared__ float BL[BL_H * BL_W];  // 26.8 KB
    int tid = threadIdx.x;
    int x0 = blockIdx.x * BS_W;
    int y0 = blockIdx.y * BS_H;
    // stage gray with +-3 halo, 0 outside image
    for (int t = tid; t < GT_H * GT_W; t += 512) {
        int ly = t / GT_W, lx = t - ly * GT_W;
        int y = y0 - 3 + ly, x = x0 - 3 + lx;
        GT[t] = ((unsigned)y < TH && (unsigned)x < TW) ? g[(size_t)y * TW + x] : 0.f;
    }
    __syncthreads();
    // blurred (exact 25-term row-major order); 0 outside image (reference
    // zero-pads BLURRED for sobel, not gray)
    for (int t = tid; t < BL_H * BL_W; t += 512) {
        int by = t / BL_W, bx = t - by * BL_W;
        int yb = y0 - 1 + by, xb = x0 - 1 + bx;
        float acc = 0.f;
        if ((unsigned)yb < TH && (unsigned)xb < TW) {
#pragma unroll
            for (int a = 0; a < 5; a++)
#pragma unroll
                for (int b = 0; b < 5; b++)
                    acc = __fadd_rn(acc, __fmul_rn(GT[(by + a) * GT_W + bx + b], 0.04f));
        }
        BL[t] = acc;
    }
    __syncthreads();
    int tx = tid & 255;
    int ty = tid >> 8;  // 0..1, each does 12 rows
    float tmax = 0.f;
#pragma unroll
    for (int k = 0; k < 12; k++) {
        int oy = ty * 12 + k;
        float v[3][3];
#pragma unroll
        for (int a = 0; a < 3; a++)
#pragma unroll
            for (int b = 0; b < 3; b++) v[a][b] = BL[(oy + a) * BL_W + tx + b];
        float gx = 0.f;
        gx = __fadd_rn(gx, __fmul_rn(-1.f, v[0][0]));
        gx = __fadd_rn(gx, v[0][2]);
        gx = __fadd_rn(gx, __fmul_rn(-2.f, v[1][0]));
        gx = __fadd_rn(gx, __fmul_rn(2.f, v[1][2]));
        gx = __fadd_rn(gx, __fmul_rn(-1.f, v[2][0]));
        gx = __fadd_rn(gx, v[2][2]);
        float gyv = 0.f;
        gyv = __fadd_rn(gyv, __fmul_rn(-1.f, v[0][0]));
        gyv = __fadd_rn(gyv, __fmul_rn(-2.f, v[0][1]));
        gyv = __fadd_rn(gyv, __fmul_rn(-1.f, v[0][2]));
        gyv = __fadd_rn(gyv, v[2][0]);
        gyv = __fadd_rn(gyv, __fmul_rn(2.f, v[2][1]));
        gyv = __fadd_rn(gyv, v[2][2]);
        float m = sqrtf(__fadd_rn(__fmul_rn(gx, gx), __fmul_rn(gyv, gyv)));
        mag[(size_t)(y0 + oy) * TW + x0 + tx] = m;
        tmax = fmaxf(tmax, m);
    }
    blockMaxMinAtomic(tmax, 0.f, &scal[0], nullptr);
}

// ---------------- pass 4: fused threshold + H-gauss + V-gauss + ed min/max ----------------
// tile: 256 cols x 32 out rows. E8 = thresholded edge map (u8) + halo(7),
// EH = horizontally-convolved float rows.
#define GS_W 256
#define GS_H 32
#define E_W 272   // 270 used
#define E_H 46
__global__ __launch_bounds__(512) void k_gauss(const float* __restrict__ mag,
                                               float* __restrict__ ed,
                                               const unsigned* __restrict__ scal,
                                               unsigned* __restrict__ scalw) {
    __shared__ float wt[15];
    __shared__ unsigned char E8[E_H * E_W];  // 12.5 KB
    __shared__ float EH[E_H * GS_W];         // 47.1 KB
    if (threadIdx.x == 0) {
        float w[15];
        float s = 0.f;
        for (int t = 0; t < 15; t++) {
            int c = t - 7;
            w[t] = expf(-(float)(c * c) * 0.125f);
            s += w[t];
        }
        for (int t = 0; t < 15; t++) wt[t] = w[t] / s;
    }
    __syncthreads();
    float magmax = __uint_as_float(scal[0]);
    float hi = __fmul_rn(magmax, 0.2f);
    float lo = __fmul_rn(hi, 0.3f);
    int tid = threadIdx.x;
    int x0 = blockIdx.x * GS_W;
    int y0 = blockIdx.y * GS_H;
    // stage thresholded edge map with +-7 halo both dims; 0 outside image
    for (int t = tid; t < E_H * 270; t += 512) {
        int ly = t / 270, lx = t - ly * 270;
        int y = y0 - 7 + ly, x = x0 - 7 + lx;
        float m = ((unsigned)y < TH && (unsigned)x < TW) ? mag[(size_t)y * TW + x] : 0.f;
        E8[ly * E_W + lx] = (m > lo && m < hi) ? 1 : 0;
    }
    __syncthreads();
    // horizontal 15-tap
    for (int t = tid; t < E_H * GS_W; t += 512) {
        int ly = t >> 8, lx = t & 255;
        float acc = 0.f;
#pragma unroll
        for (int k = 0; k < 15; k++)
            acc = fmaf((float)E8[ly * E_W + lx + k], wt[k], acc);
        EH[t] = acc;
    }
    __syncthreads();
    // vertical 15-tap + min/max
    int tx = tid & 255;
    int ty = tid >> 8;  // 0..1, each does 16 rows
    float tmin = INFINITY, tmax = 0.f;
#pragma unroll 4
    for (int k = 0; k < 16; k++) {
        int r = ty * 16 + k;
        float acc = 0.f;
#pragma unroll
        for (int t = 0; t < 15; t++) acc = fmaf(EH[(r + t) * GS_W + tx], wt[t], acc);
        ed[(size_t)(y0 + r) * TW + x0 + tx] = acc;
        tmin = fminf(tmin, acc);
        tmax = fmaxf(tmax, acc);
    }
    blockMaxMinAtomic(tmax, tmin, &scalw[2], &scalw[1]);
}

// ---------------- pass 5: normalize + color sparsity + sigmoid (vectorized) ----------------
__global__ void k_final(float4* __restrict__ io4, const ushort4* __restrict__ code4,
                        const unsigned* __restrict__ hist, const unsigned* __restrict__ scal,
                        const float* __restrict__ alphap, const float* __restrict__ betap) {
    float edmin = __uint_as_float(scal[1]);
    float edmax = __uint_as_float(scal[2]);
    float edrange = edmax - edmin + 1e-9f;
    const float N = (float)NPIX;
    float csmin = -logf((float)scal[3] / N + 1e-9f) * 1.5f;
    float csmax = -logf((float)scal[4] / N + 1e-9f) * 1.5f;
    float csrange = csmax - csmin + 1e-9f;
    float alpha = *alphap, beta = *betap;
    const int total4 = NPIX / 4;
    int stride = gridDim.x * blockDim.x;
    for (int p = blockIdx.x * blockDim.x + threadIdx.x; p < total4; p += stride) {
        float4 ed = io4[p];
        ushort4 cc = code4[p];
        float edv[4] = {ed.x, ed.y, ed.z, ed.w};
        unsigned short cv[4] = {cc.x, cc.y, cc.z, cc.w};
        float ov[4];
#pragma unroll
        for (int t = 0; t < 4; t++) {
            float en = (edv[t] - edmin) / edrange;
            float prob = (float)hist[cv[t]] / N;
            float cs = -logf(prob + 1e-9f) * 1.5f;
            float cn = (cs - csmin) / csrange;
            float x = alpha * en + beta * cn;
            ov[t] = 1.f / (1.f + expf(-x));
        }
        float4 o;
        o.x = ov[0]; o.y = ov[1]; o.z = ov[2]; o.w = ov[3];
        io4[p] = o;
    }
}

extern "C" void kernel_launch(void* const* d_in, const int* in_sizes, int n_in,
                              void* d_out, int out_size, void* d_ws, size_t ws_size,
                              hipStream_t stream) {
    const float* img = (const float*)d_in[0];
    const float* alphap = (const float*)d_in[1];
    const float* betap = (const float*)d_in[2];
    float* out = (float*)d_out;

    char* ws = (char*)d_ws;
    unsigned* scal = (unsigned*)ws;                                   // 64 B
    unsigned* hist = (unsigned*)(ws + 1024);                          // 128 KiB
    float* G = (float*)(ws + 262144);                                 // 37.75 MB (gray)
    float* M = (float*)(ws + 262144 + (size_t)NPIX * 4);              // 37.75 MB (parthist -> mag)
    unsigned short* code = (unsigned short*)(ws + 262144 + (size_t)NPIX * 8);  // 18.9 MB
    unsigned* parthist = (unsigned*)M;  // 32 MB; dead before k_boxsobel writes mag into M

    hipLaunchKernelGGL(k_init, dim3(1), dim3(64), 0, stream, scal);
    hipLaunchKernelGGL(k_pre, dim3(512), dim3(512), 0, stream,
                       (const float4*)img, (float4*)G, (ushort4*)code, parthist);
    hipLaunchKernelGGL(k_reduce, dim3(64), dim3(256), 0, stream, parthist, hist, scal);
    hipLaunchKernelGGL(k_boxsobel, dim3(TW / BS_W, TH / BS_H), dim3(512), 0, stream,
                       G, M, scal);
    hipLaunchKernelGGL(k_gauss, dim3(TW / GS_W, TH / GS_H), dim3(512), 0, stream,
                       M, out, scal, scal);
    hipLaunchKernelGGL(k_final, dim3(2304), dim3(256), 0, stream, (float4*)out,
                       (const ushort4*)code, hist, scal, alphap, betap);
}

// Round 5
// 345.721 us; speedup vs baseline: 2.7410x; 1.0852x over previous
//
#include <hip/hip_runtime.h>
#include <math.h>

#define TW 3072
#define TH 3072
#define NPIX (TW*TH)

// scal[0]=magmax bits, scal[1]=edmin bits, scal[2]=edmax bits,
// scal[3]=max hist count, scal[4]=min nonzero hist count
__global__ void k_init(unsigned* scal) {
    if (threadIdx.x == 0) {
        scal[0] = 0u;
        scal[1] = 0x7F800000u;  // +inf
        scal[2] = 0u;
        scal[3] = 0u;
        scal[4] = 0xFFFFFFFFu;
    }
}

__device__ __forceinline__ int qcode(float r, float g, float b) {
    int ir = min(max((int)rintf(__fmul_rn(r, 31.f)), 0), 31);
    int ig = min(max((int)rintf(__fmul_rn(g, 31.f)), 0), 31);
    int ib = min(max((int)rintf(__fmul_rn(b, 31.f)), 0), 31);
    return ir * 1024 + ig * 32 + ib;
}

__device__ __forceinline__ float grayf(float r, float g, float b) {
    // no FMA contraction: threshold-sensitive path must match numpy bit-closely
    return __fadd_rn(__fadd_rn(__fmul_rn(0.299f, r), __fmul_rn(0.587f, g)),
                     __fmul_rn(0.114f, b));
}

// ---------------- pass 1: gray + code + per-block LDS histogram ----------------
__global__ __launch_bounds__(512) void k_pre(const float4* __restrict__ img4,
                                             float4* __restrict__ gray4,
                                             ushort4* __restrict__ code4,
                                             unsigned* __restrict__ parthist) {
    __shared__ unsigned lh[16384];  // 64 KB: bins 2b (lo16) / 2b+1 (hi16)
    for (int t = threadIdx.x; t < 16384; t += 512) lh[t] = 0u;
    __syncthreads();
    const int total4 = NPIX / 4;
    int stride = gridDim.x * blockDim.x;
    for (int p = blockIdx.x * blockDim.x + threadIdx.x; p < total4; p += stride) {
        float4 r = img4[p], g = img4[p + total4], b = img4[p + 2 * total4];
        float4 gy;
        gy.x = grayf(r.x, g.x, b.x);
        gy.y = grayf(r.y, g.y, b.y);
        gy.z = grayf(r.z, g.z, b.z);
        gy.w = grayf(r.w, g.w, b.w);
        gray4[p] = gy;
        int c0 = qcode(r.x, g.x, b.x);
        int c1 = qcode(r.y, g.y, b.y);
        int c2 = qcode(r.z, g.z, b.z);
        int c3 = qcode(r.w, g.w, b.w);
        atomicAdd(&lh[c0 >> 1], (c0 & 1) ? 0x10000u : 1u);
        atomicAdd(&lh[c1 >> 1], (c1 & 1) ? 0x10000u : 1u);
        atomicAdd(&lh[c2 >> 1], (c2 & 1) ? 0x10000u : 1u);
        atomicAdd(&lh[c3 >> 1], (c3 & 1) ? 0x10000u : 1u);
        ushort4 cc;
        cc.x = (unsigned short)c0; cc.y = (unsigned short)c1;
        cc.z = (unsigned short)c2; cc.w = (unsigned short)c3;
        code4[p] = cc;
    }
    __syncthreads();
    unsigned* dst = parthist + (size_t)blockIdx.x * 16384;
    for (int t = threadIdx.x; t < 16384; t += 512) dst[t] = lh[t];
}

// ---------------- pass 2: reduce partials -> hist + cstab + max/min-nonzero ----------------
__global__ void k_reduce(const unsigned* __restrict__ parthist, unsigned* __restrict__ hist,
                         float* __restrict__ cstab, unsigned* __restrict__ scal) {
    int b = blockIdx.x * blockDim.x + threadIdx.x;  // 0..16383 (bin pair)
    unsigned lo = 0u, hi = 0u;
#pragma unroll 4
    for (int k = 0; k < 512; k++) {
        unsigned v = parthist[(size_t)k * 16384 + b];
        lo += v & 0xFFFFu;
        hi += v >> 16;
    }
    hist[2 * b] = lo;
    hist[2 * b + 1] = hi;
    const float N = (float)NPIX;
    // identical expression to what k_final previously computed per pixel
    cstab[2 * b]     = -logf((float)lo / N + 1e-9f) * 1.5f;
    cstab[2 * b + 1] = -logf((float)hi / N + 1e-9f) * 1.5f;
    unsigned mx = max(lo, hi);
    unsigned mn = 0xFFFFFFFFu;
    if (lo) mn = lo;
    if (hi) mn = min(mn, hi);
#pragma unroll
    for (int o = 32; o > 0; o >>= 1) {
        mx = max(mx, (unsigned)__shfl_down((int)mx, o));
        mn = min(mn, (unsigned)__shfl_down((int)mn, o));
    }
    __shared__ unsigned smx[4], smn[4];
    int lane = threadIdx.x & 63, wv = threadIdx.x >> 6;
    if (lane == 0) { smx[wv] = mx; smn[wv] = mn; }
    __syncthreads();
    if (threadIdx.x == 0) {
        unsigned a = max(max(smx[0], smx[1]), max(smx[2], smx[3]));
        unsigned c = min(min(smn[0], smn[1]), min(smn[2], smn[3]));
        atomicMax(&scal[3], a);
        atomicMin(&scal[4], c);
    }
}

// generic block max/min -> global atomics (supports 256 or 512 threads)
__device__ __forceinline__ void blockMaxMinAtomic(float vmax, float vmin,
                                                  unsigned* pmax, unsigned* pmin) {
#pragma unroll
    for (int o = 32; o > 0; o >>= 1) {
        vmax = fmaxf(vmax, __shfl_down(vmax, o));
        vmin = fminf(vmin, __shfl_down(vmin, o));
    }
    __shared__ float smax[8], smin[8];
    int lane = threadIdx.x & 63, wv = threadIdx.x >> 6;
    if (lane == 0) { smax[wv] = vmax; smin[wv] = vmin; }
    __syncthreads();
    if (threadIdx.x == 0) {
        int nw = blockDim.x >> 6;
        float a = smax[0], b = smin[0];
        for (int k = 1; k < nw; k++) { a = fmaxf(a, smax[k]); b = fminf(b, smin[k]); }
        if (pmax) atomicMax(pmax, __float_as_uint(a));
        if (pmin) atomicMin(pmin, __float_as_uint(b));
    }
}

// ---------------- pass 3: fused 5x5 box + sobel + mag + magmax ----------------
// tile: 256 cols x 24 out rows; 4 outputs/thread via b128 LDS reads.
#define BS_W 256
#define BS_H 24
#define GTW 264   // padded float stride (16B-mult); cols 0..261 meaningful
#define GTH 30
#define BLW 260   // padded float stride; cols 0..257 used by sobel
#define BLH 26
__global__ __launch_bounds__(512) void k_boxsobel(const float* __restrict__ g,
                                                  float* __restrict__ mag,
                                                  unsigned* __restrict__ scal) {
    __shared__ float GT[GTH * GTW];  // 31.7 KB
    __shared__ float BL[BLH * BLW];  // 27.0 KB
    int tid = threadIdx.x;
    int x0 = blockIdx.x * BS_W;
    int y0 = blockIdx.y * BS_H;
    // stage gray with +-3 halo, 0 outside image
    for (int t = tid; t < GTH * GTW; t += 512) {
        int ly = t / GTW, lx = t - ly * GTW;
        int y = y0 - 3 + ly, x = x0 - 3 + lx;
        GT[t] = ((unsigned)y < TH && (unsigned)x < TW) ? g[(size_t)y * TW + x] : 0.f;
    }
    __syncthreads();
    // blurred: 26 rows x 65 groups of 4 cols; exact 25-term row-major order.
    // 0 outside image (reference zero-pads BLURRED for sobel, not gray).
    for (int t = tid; t < BLH * 65; t += 512) {
        int by = t / 65, gx = t - by * 65;
        int c0 = gx * 4;
        float acc[4] = {0.f, 0.f, 0.f, 0.f};
#pragma unroll
        for (int a = 0; a < 5; a++) {
            const float* rp = &GT[(by + a) * GTW + c0];
            float4 A = *(const float4*)rp;
            float4 B = *(const float4*)(rp + 4);
            float v[8] = {A.x, A.y, A.z, A.w, B.x, B.y, B.z, B.w};
#pragma unroll
            for (int j = 0; j < 4; j++)
#pragma unroll
                for (int b = 0; b < 5; b++)
                    acc[j] = __fadd_rn(acc[j], __fmul_rn(v[j + b], 0.04f));
        }
        int yb = y0 - 1 + by;
        float4 o;
        float* ov = (float*)&o;
#pragma unroll
        for (int j = 0; j < 4; j++) {
            int xb = x0 - 1 + c0 + j;
            ov[j] = ((unsigned)yb < TH && (unsigned)xb < TW) ? acc[j] : 0.f;
        }
        *(float4*)&BL[by * BLW + c0] = o;
    }
    __syncthreads();
    // sobel: 24 rows x 64 groups of 4 cols
    float tmax = 0.f;
    for (int t = tid; t < 24 * 64; t += 512) {
        int oy = t >> 6, gx = t & 63;
        int c0 = gx * 4;
        float v[3][6];
#pragma unroll
        for (int a = 0; a < 3; a++) {
            const float* rp = &BL[(oy + a) * BLW + c0];
            float4 P = *(const float4*)rp;
            float2 Q = *(const float2*)(rp + 4);
            v[a][0] = P.x; v[a][1] = P.y; v[a][2] = P.z; v[a][3] = P.w;
            v[a][4] = Q.x; v[a][5] = Q.y;
        }
        float4 mo;
        float* mv = (float*)&mo;
#pragma unroll
        for (int j = 0; j < 4; j++) {
            float gxv = 0.f;
            gxv = __fadd_rn(gxv, __fmul_rn(-1.f, v[0][j + 0]));
            gxv = __fadd_rn(gxv, v[0][j + 2]);
            gxv = __fadd_rn(gxv, __fmul_rn(-2.f, v[1][j + 0]));
            gxv = __fadd_rn(gxv, __fmul_rn(2.f, v[1][j + 2]));
            gxv = __fadd_rn(gxv, __fmul_rn(-1.f, v[2][j + 0]));
            gxv = __fadd_rn(gxv, v[2][j + 2]);
            float gyv = 0.f;
            gyv = __fadd_rn(gyv, __fmul_rn(-1.f, v[0][j + 0]));
            gyv = __fadd_rn(gyv, __fmul_rn(-2.f, v[0][j + 1]));
            gyv = __fadd_rn(gyv, __fmul_rn(-1.f, v[0][j + 2]));
            gyv = __fadd_rn(gyv, v[2][j + 0]);
            gyv = __fadd_rn(gyv, __fmul_rn(2.f, v[2][j + 1]));
            gyv = __fadd_rn(gyv, v[2][j + 2]);
            float m = sqrtf(__fadd_rn(__fmul_rn(gxv, gxv), __fmul_rn(gyv, gyv)));
            mv[j] = m;
            tmax = fmaxf(tmax, m);
        }
        *(float4*)&mag[(size_t)(y0 + oy) * TW + x0 + c0] = mo;
    }
    blockMaxMinAtomic(tmax, 0.f, &scal[0], nullptr);
}

// ---------------- pass 4: fused threshold + H-gauss + V-gauss + ed min/max ----------------
// tile: 256 cols x 32 out rows; packed-u8 edge map, 4 outputs/thread.
#define GS_W 256
#define GS_H 32
#define EW32 68   // u32 words per edge row (272 bytes, 270 used)
#define E_H 46
__global__ __launch_bounds__(512) void k_gauss(const float* __restrict__ mag,
                                               float* __restrict__ ed,
                                               const unsigned* __restrict__ scal,
                                               unsigned* __restrict__ scalw) {
    __shared__ float wt[15];
    __shared__ unsigned E8[E_H * EW32];  // 12.2 KB packed edge bytes
    __shared__ float EH[E_H * GS_W];     // 47.1 KB
    if (threadIdx.x == 0) {
        float w[15];
        float s = 0.f;
        for (int t = 0; t < 15; t++) {
            int c = t - 7;
            w[t] = expf(-(float)(c * c) * 0.125f);
            s += w[t];
        }
        for (int t = 0; t < 15; t++) wt[t] = w[t] / s;
    }
    __syncthreads();
    float magmax = __uint_as_float(scal[0]);
    float hi = __fmul_rn(magmax, 0.2f);
    float lo = __fmul_rn(hi, 0.3f);
    int tid = threadIdx.x;
    int x0 = blockIdx.x * GS_W;
    int y0 = blockIdx.y * GS_H;
    // stage thresholded edge map (packed 4 bytes/word); 0 outside image
    for (int t = tid; t < E_H * EW32; t += 512) {
        int ly = t / EW32, w = t - ly * EW32;
        int y = y0 - 7 + ly;
        bool yin = (unsigned)y < TH;
        const float* mrow = mag + (size_t)y * TW;
        int xbase = x0 - 7 + w * 4;
        unsigned pack = 0u;
#pragma unroll
        for (int j = 0; j < 4; j++) {
            int x = xbase + j;
            float m = (yin && (unsigned)x < TW) ? mrow[x] : 0.f;
            if (m > lo && m < hi) pack |= 1u << (8 * j);
        }
        E8[t] = pack;
    }
    __syncthreads();
    // horizontal 15-tap: 46 rows x 64 groups of 4 cols; 5 b32 reads/group
    for (int t = tid; t < E_H * 64; t += 512) {
        int ly = t >> 6, gx = t & 63;
        int c0 = gx * 4;
        const unsigned* row = &E8[ly * EW32 + gx];
        unsigned w0 = row[0], w1 = row[1], w2 = row[2], w3 = row[3], w4 = row[4];
        float e[20];
#pragma unroll
        for (int j = 0; j < 4; j++) {
            e[j]      = (float)((w0 >> (8 * j)) & 0xffu);
            e[4 + j]  = (float)((w1 >> (8 * j)) & 0xffu);
            e[8 + j]  = (float)((w2 >> (8 * j)) & 0xffu);
            e[12 + j] = (float)((w3 >> (8 * j)) & 0xffu);
            e[16 + j] = (float)((w4 >> (8 * j)) & 0xffu);
        }
        float4 o;
        float* ov = (float*)&o;
#pragma unroll
        for (int j = 0; j < 4; j++) {
            float acc = 0.f;
#pragma unroll
            for (int k = 0; k < 15; k++) acc = fmaf(e[j + k], wt[k], acc);
            ov[j] = acc;
        }
        *(float4*)&EH[ly * GS_W + c0] = o;
    }
    __syncthreads();
    // vertical 15-tap + min/max: 32 rows x 64 groups of 4; 15 b128 reads/group
    float tmin = INFINITY, tmax = 0.f;
    for (int t = tid; t < GS_H * 64; t += 512) {
        int r = t >> 6, gx = t & 63;
        int c0 = gx * 4;
        float a0 = 0.f, a1 = 0.f, a2 = 0.f, a3 = 0.f;
#pragma unroll
        for (int k = 0; k < 15; k++) {
            float4 v = *(const float4*)&EH[(r + k) * GS_W + c0];
            a0 = fmaf(v.x, wt[k], a0);
            a1 = fmaf(v.y, wt[k], a1);
            a2 = fmaf(v.z, wt[k], a2);
            a3 = fmaf(v.w, wt[k], a3);
        }
        float4 o; o.x = a0; o.y = a1; o.z = a2; o.w = a3;
        *(float4*)&ed[(size_t)(y0 + r) * TW + x0 + c0] = o;
        tmin = fminf(tmin, fminf(fminf(a0, a1), fminf(a2, a3)));
        tmax = fmaxf(tmax, fmaxf(fmaxf(a0, a1), fmaxf(a2, a3)));
    }
    blockMaxMinAtomic(tmax, tmin, &scalw[2], &scalw[1]);
}

// ---------------- pass 5: normalize + color sparsity + sigmoid (vectorized) ----------------
__global__ void k_final(float4* __restrict__ io4, const ushort4* __restrict__ code4,
                        const float* __restrict__ cstab, const unsigned* __restrict__ scal,
                        const float* __restrict__ alphap, const float* __restrict__ betap) {
    float edmin = __uint_as_float(scal[1]);
    float edmax = __uint_as_float(scal[2]);
    float edrange = edmax - edmin + 1e-9f;
    const float N = (float)NPIX;
    float csmin = -logf((float)scal[3] / N + 1e-9f) * 1.5f;
    float csmax = -logf((float)scal[4] / N + 1e-9f) * 1.5f;
    float csrange = csmax - csmin + 1e-9f;
    float alpha = *alphap, beta = *betap;
    const int total4 = NPIX / 4;
    int stride = gridDim.x * blockDim.x;
    for (int p = blockIdx.x * blockDim.x + threadIdx.x; p < total4; p += stride) {
        float4 ed = io4[p];
        ushort4 cc = code4[p];
        float edv[4] = {ed.x, ed.y, ed.z, ed.w};
        unsigned short cv[4] = {cc.x, cc.y, cc.z, cc.w};
        float ov[4];
#pragma unroll
        for (int t = 0; t < 4; t++) {
            float en = (edv[t] - edmin) / edrange;
            float cs = cstab[cv[t]];
            float cn = (cs - csmin) / csrange;
            float x = alpha * en + beta * cn;
            ov[t] = 1.f / (1.f + expf(-x));
        }
        float4 o;
        o.x = ov[0]; o.y = ov[1]; o.z = ov[2]; o.w = ov[3];
        io4[p] = o;
    }
}

extern "C" void kernel_launch(void* const* d_in, const int* in_sizes, int n_in,
                              void* d_out, int out_size, void* d_ws, size_t ws_size,
                              hipStream_t stream) {
    const float* img = (const float*)d_in[0];
    const float* alphap = (const float*)d_in[1];
    const float* betap = (const float*)d_in[2];
    float* out = (float*)d_out;

    char* ws = (char*)d_ws;
    unsigned* scal = (unsigned*)ws;                                  // 64 B
    unsigned* hist = (unsigned*)(ws + 1024);                         // 128 KiB
    float* cstab = (float*)(ws + 1024 + 131072);                     // 128 KiB
    float* G = (float*)(ws + 524288);                                // 37.75 MB (gray)
    float* M = (float*)(ws + 524288 + (size_t)NPIX * 4);             // 37.75 MB (parthist -> mag)
    unsigned short* code = (unsigned short*)(ws + 524288 + (size_t)NPIX * 8);  // 18.9 MB
    unsigned* parthist = (unsigned*)M;  // 32 MB alias; dead before k_boxsobel writes mag

    hipLaunchKernelGGL(k_init, dim3(1), dim3(64), 0, stream, scal);
    hipLaunchKernelGGL(k_pre, dim3(512), dim3(512), 0, stream,
                       (const float4*)img, (float4*)G, (ushort4*)code, parthist);
    hipLaunchKernelGGL(k_reduce, dim3(64), dim3(256), 0, stream, parthist, hist, cstab, scal);
    hipLaunchKernelGGL(k_boxsobel, dim3(TW / BS_W, TH / BS_H), dim3(512), 0, stream,
                       G, M, scal);
    hipLaunchKernelGGL(k_gauss, dim3(TW / GS_W, TH / GS_H), dim3(512), 0, stream,
                       M, out, scal, scal);
    hipLaunchKernelGGL(k_final, dim3(2304), dim3(256), 0, stream, (float4*)out,
                       (const ushort4*)code, cstab, scal, alphap, betap);
}

// Round 6
// 344.679 us; speedup vs baseline: 2.7493x; 1.0030x over previous
//
#include <hip/hip_runtime.h>
#include <math.h>

#define TW 3072
#define TH 3072
#define NPIX (TW*TH)

__device__ __forceinline__ int qcode(float r, float g, float b) {
    int ir = min(max((int)rintf(__fmul_rn(r, 31.f)), 0), 31);
    int ig = min(max((int)rintf(__fmul_rn(g, 31.f)), 0), 31);
    int ib = min(max((int)rintf(__fmul_rn(b, 31.f)), 0), 31);
    return ir * 1024 + ig * 32 + ib;
}

__device__ __forceinline__ float grayf(float r, float g, float b) {
    // no FMA contraction: threshold-sensitive path must match numpy bit-closely
    return __fadd_rn(__fadd_rn(__fmul_rn(0.299f, r), __fmul_rn(0.587f, g)),
                     __fmul_rn(0.114f, b));
}

// ---------------- pass 1: init scalars + gray + code + per-block LDS histogram ----------------
// scal[0]=magmax bits, scal[1]=edmin bits, scal[2]=edmax bits,
// scal[3]=max hist count, scal[4]=min nonzero hist count.
// 512 blocks x 512 threads; <=18432 px/block so per-bin block counts fit u16.
__global__ __launch_bounds__(512) void k_pre(const float4* __restrict__ img4,
                                             float4* __restrict__ gray4,
                                             ushort4* __restrict__ code4,
                                             unsigned* __restrict__ parthist,
                                             unsigned* __restrict__ scal) {
    if (blockIdx.x == 0 && threadIdx.x == 0) {
        scal[0] = 0u;
        scal[1] = 0x7F800000u;  // +inf
        scal[2] = 0u;
        scal[3] = 0u;
        scal[4] = 0xFFFFFFFFu;
    }
    __shared__ unsigned lh[16384];  // 64 KB: bins 2b (lo16) / 2b+1 (hi16)
    for (int t = threadIdx.x; t < 16384; t += 512) lh[t] = 0u;
    __syncthreads();
    const int total4 = NPIX / 4;          // 2359296
    const int stride = 512 * 512;         // 262144 threads; 9 elems/thread
    int base = blockIdx.x * 512 + threadIdx.x;
    // 4 double-iterations + 1 tail = 9; pairs give 6 loads in flight
#pragma unroll
    for (int k = 0; k < 8; k += 2) {
        int p = base + k * stride;
        int q = p + stride;
        float4 r0 = img4[p], g0 = img4[p + total4], b0 = img4[p + 2 * total4];
        float4 r1 = img4[q], g1 = img4[q + total4], b1 = img4[q + 2 * total4];
        float4 gy0, gy1;
        gy0.x = grayf(r0.x, g0.x, b0.x); gy0.y = grayf(r0.y, g0.y, b0.y);
        gy0.z = grayf(r0.z, g0.z, b0.z); gy0.w = grayf(r0.w, g0.w, b0.w);
        gy1.x = grayf(r1.x, g1.x, b1.x); gy1.y = grayf(r1.y, g1.y, b1.y);
        gy1.z = grayf(r1.z, g1.z, b1.z); gy1.w = grayf(r1.w, g1.w, b1.w);
        gray4[p] = gy0;
        gray4[q] = gy1;
        int c0 = qcode(r0.x, g0.x, b0.x), c1 = qcode(r0.y, g0.y, b0.y);
        int c2 = qcode(r0.z, g0.z, b0.z), c3 = qcode(r0.w, g0.w, b0.w);
        int d0 = qcode(r1.x, g1.x, b1.x), d1 = qcode(r1.y, g1.y, b1.y);
        int d2 = qcode(r1.z, g1.z, b1.z), d3 = qcode(r1.w, g1.w, b1.w);
        atomicAdd(&lh[c0 >> 1], (c0 & 1) ? 0x10000u : 1u);
        atomicAdd(&lh[c1 >> 1], (c1 & 1) ? 0x10000u : 1u);
        atomicAdd(&lh[c2 >> 1], (c2 & 1) ? 0x10000u : 1u);
        atomicAdd(&lh[c3 >> 1], (c3 & 1) ? 0x10000u : 1u);
        atomicAdd(&lh[d0 >> 1], (d0 & 1) ? 0x10000u : 1u);
        atomicAdd(&lh[d1 >> 1], (d1 & 1) ? 0x10000u : 1u);
        atomicAdd(&lh[d2 >> 1], (d2 & 1) ? 0x10000u : 1u);
        atomicAdd(&lh[d3 >> 1], (d3 & 1) ? 0x10000u : 1u);
        ushort4 cc, dd;
        cc.x = (unsigned short)c0; cc.y = (unsigned short)c1;
        cc.z = (unsigned short)c2; cc.w = (unsigned short)c3;
        dd.x = (unsigned short)d0; dd.y = (unsigned short)d1;
        dd.z = (unsigned short)d2; dd.w = (unsigned short)d3;
        code4[p] = cc;
        code4[q] = dd;
    }
    {   // tail: element 8
        int p = base + 8 * stride;
        float4 r = img4[p], g = img4[p + total4], b = img4[p + 2 * total4];
        float4 gy;
        gy.x = grayf(r.x, g.x, b.x); gy.y = grayf(r.y, g.y, b.y);
        gy.z = grayf(r.z, g.z, b.z); gy.w = grayf(r.w, g.w, b.w);
        gray4[p] = gy;
        int c0 = qcode(r.x, g.x, b.x), c1 = qcode(r.y, g.y, b.y);
        int c2 = qcode(r.z, g.z, b.z), c3 = qcode(r.w, g.w, b.w);
        atomicAdd(&lh[c0 >> 1], (c0 & 1) ? 0x10000u : 1u);
        atomicAdd(&lh[c1 >> 1], (c1 & 1) ? 0x10000u : 1u);
        atomicAdd(&lh[c2 >> 1], (c2 & 1) ? 0x10000u : 1u);
        atomicAdd(&lh[c3 >> 1], (c3 & 1) ? 0x10000u : 1u);
        ushort4 cc;
        cc.x = (unsigned short)c0; cc.y = (unsigned short)c1;
        cc.z = (unsigned short)c2; cc.w = (unsigned short)c3;
        code4[p] = cc;
    }
    __syncthreads();
    unsigned* dst = parthist + (size_t)blockIdx.x * 16384;
    for (int t = threadIdx.x; t < 16384; t += 512) dst[t] = lh[t];
}

// ---------------- pass 2: reduce partials -> hist + cstab + max/min-nonzero ----------------
__global__ void k_reduce(const unsigned* __restrict__ parthist, unsigned* __restrict__ hist,
                         float* __restrict__ cstab, unsigned* __restrict__ scal) {
    int b = blockIdx.x * blockDim.x + threadIdx.x;  // 0..16383 (bin pair)
    unsigned lo = 0u, hi = 0u;
#pragma unroll 4
    for (int k = 0; k < 512; k++) {
        unsigned v = parthist[(size_t)k * 16384 + b];
        lo += v & 0xFFFFu;
        hi += v >> 16;
    }
    hist[2 * b] = lo;
    hist[2 * b + 1] = hi;
    const float N = (float)NPIX;
    // identical expression to the per-pixel original
    cstab[2 * b]     = -logf((float)lo / N + 1e-9f) * 1.5f;
    cstab[2 * b + 1] = -logf((float)hi / N + 1e-9f) * 1.5f;
    unsigned mx = max(lo, hi);
    unsigned mn = 0xFFFFFFFFu;
    if (lo) mn = lo;
    if (hi) mn = min(mn, hi);
#pragma unroll
    for (int o = 32; o > 0; o >>= 1) {
        mx = max(mx, (unsigned)__shfl_down((int)mx, o));
        mn = min(mn, (unsigned)__shfl_down((int)mn, o));
    }
    __shared__ unsigned smx[4], smn[4];
    int lane = threadIdx.x & 63, wv = threadIdx.x >> 6;
    if (lane == 0) { smx[wv] = mx; smn[wv] = mn; }
    __syncthreads();
    if (threadIdx.x == 0) {
        unsigned a = max(max(smx[0], smx[1]), max(smx[2], smx[3]));
        unsigned c = min(min(smn[0], smn[1]), min(smn[2], smn[3]));
        atomicMax(&scal[3], a);
        atomicMin(&scal[4], c);
    }
}

// generic block max/min -> global atomics (supports 256 or 512 threads)
__device__ __forceinline__ void blockMaxMinAtomic(float vmax, float vmin,
                                                  unsigned* pmax, unsigned* pmin) {
#pragma unroll
    for (int o = 32; o > 0; o >>= 1) {
        vmax = fmaxf(vmax, __shfl_down(vmax, o));
        vmin = fminf(vmin, __shfl_down(vmin, o));
    }
    __shared__ float smax[8], smin[8];
    int lane = threadIdx.x & 63, wv = threadIdx.x >> 6;
    if (lane == 0) { smax[wv] = vmax; smin[wv] = vmin; }
    __syncthreads();
    if (threadIdx.x == 0) {
        int nw = blockDim.x >> 6;
        float a = smax[0], b = smin[0];
        for (int k = 1; k < nw; k++) { a = fmaxf(a, smax[k]); b = fminf(b, smin[k]); }
        if (pmax) atomicMax(pmax, __float_as_uint(a));
        if (pmin) atomicMin(pmin, __float_as_uint(b));
    }
}

// ---------------- pass 3: fused 5x5 box + sobel + mag + magmax ----------------
#define BS_W 256
#define BS_H 24
#define GTW 264
#define GTH 30
#define BLW 260
#define BLH 26
__global__ __launch_bounds__(512) void k_boxsobel(const float* __restrict__ g,
                                                  float* __restrict__ mag,
                                                  unsigned* __restrict__ scal) {
    __shared__ float GT[GTH * GTW];  // 31.7 KB
    __shared__ float BL[BLH * BLW];  // 27.0 KB
    int tid = threadIdx.x;
    int x0 = blockIdx.x * BS_W;
    int y0 = blockIdx.y * BS_H;
    for (int t = tid; t < GTH * GTW; t += 512) {
        int ly = t / GTW, lx = t - ly * GTW;
        int y = y0 - 3 + ly, x = x0 - 3 + lx;
        GT[t] = ((unsigned)y < TH && (unsigned)x < TW) ? g[(size_t)y * TW + x] : 0.f;
    }
    __syncthreads();
    // blurred: exact 25-term row-major order; 0 outside image (reference
    // zero-pads BLURRED for sobel, not gray)
    for (int t = tid; t < BLH * 65; t += 512) {
        int by = t / 65, gx = t - by * 65;
        int c0 = gx * 4;
        float acc[4] = {0.f, 0.f, 0.f, 0.f};
#pragma unroll
        for (int a = 0; a < 5; a++) {
            const float* rp = &GT[(by + a) * GTW + c0];
            float4 A = *(const float4*)rp;
            float4 B = *(const float4*)(rp + 4);
            float v[8] = {A.x, A.y, A.z, A.w, B.x, B.y, B.z, B.w};
#pragma unroll
            for (int j = 0; j < 4; j++)
#pragma unroll
                for (int b = 0; b < 5; b++)
                    acc[j] = __fadd_rn(acc[j], __fmul_rn(v[j + b], 0.04f));
        }
        int yb = y0 - 1 + by;
        float4 o;
        float* ov = (float*)&o;
#pragma unroll
        for (int j = 0; j < 4; j++) {
            int xb = x0 - 1 + c0 + j;
            ov[j] = ((unsigned)yb < TH && (unsigned)xb < TW) ? acc[j] : 0.f;
        }
        *(float4*)&BL[by * BLW + c0] = o;
    }
    __syncthreads();
    float tmax = 0.f;
    for (int t = tid; t < 24 * 64; t += 512) {
        int oy = t >> 6, gx = t & 63;
        int c0 = gx * 4;
        float v[3][6];
#pragma unroll
        for (int a = 0; a < 3; a++) {
            const float* rp = &BL[(oy + a) * BLW + c0];
            float4 P = *(const float4*)rp;
            float2 Q = *(const float2*)(rp + 4);
            v[a][0] = P.x; v[a][1] = P.y; v[a][2] = P.z; v[a][3] = P.w;
            v[a][4] = Q.x; v[a][5] = Q.y;
        }
        float4 mo;
        float* mv = (float*)&mo;
#pragma unroll
        for (int j = 0; j < 4; j++) {
            float gxv = 0.f;
            gxv = __fadd_rn(gxv, __fmul_rn(-1.f, v[0][j + 0]));
            gxv = __fadd_rn(gxv, v[0][j + 2]);
            gxv = __fadd_rn(gxv, __fmul_rn(-2.f, v[1][j + 0]));
            gxv = __fadd_rn(gxv, __fmul_rn(2.f, v[1][j + 2]));
            gxv = __fadd_rn(gxv, __fmul_rn(-1.f, v[2][j + 0]));
            gxv = __fadd_rn(gxv, v[2][j + 2]);
            float gyv = 0.f;
            gyv = __fadd_rn(gyv, __fmul_rn(-1.f, v[0][j + 0]));
            gyv = __fadd_rn(gyv, __fmul_rn(-2.f, v[0][j + 1]));
            gyv = __fadd_rn(gyv, __fmul_rn(-1.f, v[0][j + 2]));
            gyv = __fadd_rn(gyv, v[2][j + 0]);
            gyv = __fadd_rn(gyv, __fmul_rn(2.f, v[2][j + 1]));
            gyv = __fadd_rn(gyv, v[2][j + 2]);
            float m = sqrtf(__fadd_rn(__fmul_rn(gxv, gxv), __fmul_rn(gyv, gyv)));
            mv[j] = m;
            tmax = fmaxf(tmax, m);
        }
        *(float4*)&mag[(size_t)(y0 + oy) * TW + x0 + c0] = mo;
    }
    blockMaxMinAtomic(tmax, 0.f, &scal[0], nullptr);
}

// ---------------- pass 4: fused threshold + H-gauss + V-gauss + ed min/max ----------------
// tile: 256 cols x 48 out rows; edge map packed 1 BIT/px (270 bits -> 10 u32/row).
#define GS_W 256
#define GS_H 48
#define E_H 62
#define EWB 10
__global__ __launch_bounds__(512) void k_gauss(const float* __restrict__ mag,
                                               float* __restrict__ ed,
                                               const unsigned* __restrict__ scal,
                                               unsigned* __restrict__ scalw) {
    __shared__ float wt[15];
    __shared__ unsigned E8[E_H * EWB];   // 2.4 KB bit-packed edge map
    __shared__ float EH[E_H * GS_W];     // 63.5 KB
    if (threadIdx.x == 0) {
        float w[15];
        float s = 0.f;
        for (int t = 0; t < 15; t++) {
            int c = t - 7;
            w[t] = expf(-(float)(c * c) * 0.125f);
            s += w[t];
        }
        for (int t = 0; t < 15; t++) wt[t] = w[t] / s;
    }
    __syncthreads();
    float magmax = __uint_as_float(scal[0]);
    float hi = __fmul_rn(magmax, 0.2f);
    float lo = __fmul_rn(hi, 0.3f);
    int tid = threadIdx.x;
    int x0 = blockIdx.x * GS_W;
    int y0 = blockIdx.y * GS_H;
    // stage thresholded edge map, 1 bit/px; 0 outside image / beyond col 269
    for (int t = tid; t < E_H * EWB; t += 512) {
        int ly = t / EWB, w = t - ly * EWB;
        int y = y0 - 7 + ly;
        bool yin = (unsigned)y < TH;
        const float* mrow = mag + (size_t)y * TW;
        int xbase = x0 - 7 + w * 32;
        unsigned pack = 0u;
#pragma unroll
        for (int j = 0; j < 32; j++) {
            int lx = w * 32 + j;
            int x = xbase + j;
            float m = (yin && lx < 270 && (unsigned)x < TW) ? mrow[x] : 0.f;
            if (m > lo && m < hi) pack |= 1u << j;
        }
        E8[t] = pack;
    }
    __syncthreads();
    // horizontal 15-tap: 62 rows x 64 groups of 4 cols; 2 b32 reads/group
    for (int t = tid; t < E_H * 64; t += 512) {
        int ly = t >> 6, gx = t & 63;
        int c0 = gx * 4;
        int w0 = c0 >> 5, sh = c0 & 31;
        unsigned lo32 = E8[ly * EWB + w0];
        unsigned hi32 = E8[ly * EWB + w0 + 1];
        unsigned long long win = (((unsigned long long)hi32 << 32) | lo32) >> sh;
        float e[18];
#pragma unroll
        for (int j = 0; j < 18; j++) e[j] = (float)((unsigned)(win >> j) & 1u);
        float4 o;
        float* ov = (float*)&o;
#pragma unroll
        for (int j = 0; j < 4; j++) {
            float acc = 0.f;
#pragma unroll
            for (int k = 0; k < 15; k++) acc = fmaf(e[j + k], wt[k], acc);
            ov[j] = acc;
        }
        *(float4*)&EH[ly * GS_W + c0] = o;
    }
    __syncthreads();
    // vertical 15-tap + min/max: 48 rows x 64 groups of 4; 15 b128 reads/group
    float tmin = INFINITY, tmax = 0.f;
    for (int t = tid; t < GS_H * 64; t += 512) {
        int r = t >> 6, gx = t & 63;
        int c0 = gx * 4;
        float a0 = 0.f, a1 = 0.f, a2 = 0.f, a3 = 0.f;
#pragma unroll
        for (int k = 0; k < 15; k++) {
            float4 v = *(const float4*)&EH[(r + k) * GS_W + c0];
            a0 = fmaf(v.x, wt[k], a0);
            a1 = fmaf(v.y, wt[k], a1);
            a2 = fmaf(v.z, wt[k], a2);
            a3 = fmaf(v.w, wt[k], a3);
        }
        float4 o; o.x = a0; o.y = a1; o.z = a2; o.w = a3;
        *(float4*)&ed[(size_t)(y0 + r) * TW + x0 + c0] = o;
        tmin = fminf(tmin, fminf(fminf(a0, a1), fminf(a2, a3)));
        tmax = fmaxf(tmax, fmaxf(fmaxf(a0, a1), fmaxf(a2, a3)));
    }
    blockMaxMinAtomic(tmax, tmin, &scalw[2], &scalw[1]);
}

// ---------------- pass 5: normalize + color sparsity + sigmoid (vectorized) ----------------
__global__ void k_final(float4* __restrict__ io4, const ushort4* __restrict__ code4,
                        const float* __restrict__ cstab, const unsigned* __restrict__ scal,
                        const float* __restrict__ alphap, const float* __restrict__ betap) {
    float edmin = __uint_as_float(scal[1]);
    float edmax = __uint_as_float(scal[2]);
    float edrange = edmax - edmin + 1e-9f;
    const float N = (float)NPIX;
    float csmin = -logf((float)scal[3] / N + 1e-9f) * 1.5f;
    float csmax = -logf((float)scal[4] / N + 1e-9f) * 1.5f;
    float csrange = csmax - csmin + 1e-9f;
    float alpha = *alphap, beta = *betap;
    const int total4 = NPIX / 4;
    int stride = gridDim.x * blockDim.x;
    for (int p = blockIdx.x * blockDim.x + threadIdx.x; p < total4; p += stride) {
        float4 ed = io4[p];
        ushort4 cc = code4[p];
        float edv[4] = {ed.x, ed.y, ed.z, ed.w};
        unsigned short cv[4] = {cc.x, cc.y, cc.z, cc.w};
        float ov[4];
#pragma unroll
        for (int t = 0; t < 4; t++) {
            float en = (edv[t] - edmin) / edrange;
            float cs = cstab[cv[t]];
            float cn = (cs - csmin) / csrange;
            float x = alpha * en + beta * cn;
            ov[t] = 1.f / (1.f + expf(-x));
        }
        float4 o;
        o.x = ov[0]; o.y = ov[1]; o.z = ov[2]; o.w = ov[3];
        io4[p] = o;
    }
}

extern "C" void kernel_launch(void* const* d_in, const int* in_sizes, int n_in,
                              void* d_out, int out_size, void* d_ws, size_t ws_size,
                              hipStream_t stream) {
    const float* img = (const float*)d_in[0];
    const float* alphap = (const float*)d_in[1];
    const float* betap = (const float*)d_in[2];
    float* out = (float*)d_out;

    char* ws = (char*)d_ws;
    unsigned* scal = (unsigned*)ws;                                  // 64 B
    unsigned* hist = (unsigned*)(ws + 1024);                         // 128 KiB
    float* cstab = (float*)(ws + 1024 + 131072);                     // 128 KiB
    float* G = (float*)(ws + 524288);                                // 37.75 MB (gray)
    float* M = (float*)(ws + 524288 + (size_t)NPIX * 4);             // 37.75 MB (parthist -> mag)
    unsigned short* code = (unsigned short*)(ws + 524288 + (size_t)NPIX * 8);  // 18.9 MB
    unsigned* parthist = (unsigned*)M;  // 32 MB alias; dead before k_boxsobel writes mag

    hipLaunchKernelGGL(k_pre, dim3(512), dim3(512), 0, stream,
                       (const float4*)img, (float4*)G, (ushort4*)code, parthist, scal);
    hipLaunchKernelGGL(k_reduce, dim3(64), dim3(256), 0, stream, parthist, hist, cstab, scal);
    hipLaunchKernelGGL(k_boxsobel, dim3(TW / BS_W, TH / BS_H), dim3(512), 0, stream,
                       G, M, scal);
    hipLaunchKernelGGL(k_gauss, dim3(TW / GS_W, TH / GS_H), dim3(512), 0, stream,
                       M, out, scal, scal);
    hipLaunchKernelGGL(k_final, dim3(2304), dim3(256), 0, stream, (float4*)out,
                       (const ushort4*)code, cstab, scal, alphap, betap);
}

// Round 7
// 337.038 us; speedup vs baseline: 2.8116x; 1.0227x over previous
//
#include <hip/hip_runtime.h>
#include <math.h>

#define TW 3072
#define TH 3072
#define NPIX (TW*TH)

__device__ __forceinline__ int qcode(float r, float g, float b) {
    int ir = min(max((int)rintf(__fmul_rn(r, 31.f)), 0), 31);
    int ig = min(max((int)rintf(__fmul_rn(g, 31.f)), 0), 31);
    int ib = min(max((int)rintf(__fmul_rn(b, 31.f)), 0), 31);
    return ir * 1024 + ig * 32 + ib;
}

__device__ __forceinline__ float grayf(float r, float g, float b) {
    // no FMA contraction: threshold-sensitive path must match numpy bit-closely
    return __fadd_rn(__fadd_rn(__fmul_rn(0.299f, r), __fmul_rn(0.587f, g)),
                     __fmul_rn(0.114f, b));
}

// ---------------- pass 1: init scalars + gray + code + per-block LDS histogram ----------------
// scal[0]=magmax bits, scal[1]=edmin bits, scal[2]=edmax bits,
// scal[3]=max hist count, scal[4]=min nonzero hist count.
// 256 blocks x 1024 threads; 36864 px/block so per-bin block counts fit u16.
__global__ __launch_bounds__(1024) void k_pre(const float4* __restrict__ img4,
                                              float4* __restrict__ gray4,
                                              ushort4* __restrict__ code4,
                                              unsigned* __restrict__ parthist,
                                              unsigned* __restrict__ scal) {
    if (blockIdx.x == 0 && threadIdx.x == 0) {
        scal[0] = 0u;
        scal[1] = 0x7F800000u;  // +inf
        scal[2] = 0u;
        scal[3] = 0u;
        scal[4] = 0xFFFFFFFFu;
    }
    __shared__ unsigned lh[16384];  // 64 KB: bins 2b (lo16) / 2b+1 (hi16)
    for (int t = threadIdx.x; t < 16384; t += 1024) lh[t] = 0u;
    __syncthreads();
    const int total4 = NPIX / 4;          // 2359296
    const int stride = 256 * 1024;        // 262144 threads; 9 elems/thread
    int base = blockIdx.x * 1024 + threadIdx.x;
#pragma unroll
    for (int k = 0; k < 8; k += 2) {
        int p = base + k * stride;
        int q = p + stride;
        float4 r0 = img4[p], g0 = img4[p + total4], b0 = img4[p + 2 * total4];
        float4 r1 = img4[q], g1 = img4[q + total4], b1 = img4[q + 2 * total4];
        float4 gy0, gy1;
        gy0.x = grayf(r0.x, g0.x, b0.x); gy0.y = grayf(r0.y, g0.y, b0.y);
        gy0.z = grayf(r0.z, g0.z, b0.z); gy0.w = grayf(r0.w, g0.w, b0.w);
        gy1.x = grayf(r1.x, g1.x, b1.x); gy1.y = grayf(r1.y, g1.y, b1.y);
        gy1.z = grayf(r1.z, g1.z, b1.z); gy1.w = grayf(r1.w, g1.w, b1.w);
        gray4[p] = gy0;
        gray4[q] = gy1;
        int c0 = qcode(r0.x, g0.x, b0.x), c1 = qcode(r0.y, g0.y, b0.y);
        int c2 = qcode(r0.z, g0.z, b0.z), c3 = qcode(r0.w, g0.w, b0.w);
        int d0 = qcode(r1.x, g1.x, b1.x), d1 = qcode(r1.y, g1.y, b1.y);
        int d2 = qcode(r1.z, g1.z, b1.z), d3 = qcode(r1.w, g1.w, b1.w);
        atomicAdd(&lh[c0 >> 1], (c0 & 1) ? 0x10000u : 1u);
        atomicAdd(&lh[c1 >> 1], (c1 & 1) ? 0x10000u : 1u);
        atomicAdd(&lh[c2 >> 1], (c2 & 1) ? 0x10000u : 1u);
        atomicAdd(&lh[c3 >> 1], (c3 & 1) ? 0x10000u : 1u);
        atomicAdd(&lh[d0 >> 1], (d0 & 1) ? 0x10000u : 1u);
        atomicAdd(&lh[d1 >> 1], (d1 & 1) ? 0x10000u : 1u);
        atomicAdd(&lh[d2 >> 1], (d2 & 1) ? 0x10000u : 1u);
        atomicAdd(&lh[d3 >> 1], (d3 & 1) ? 0x10000u : 1u);
        ushort4 cc, dd;
        cc.x = (unsigned short)c0; cc.y = (unsigned short)c1;
        cc.z = (unsigned short)c2; cc.w = (unsigned short)c3;
        dd.x = (unsigned short)d0; dd.y = (unsigned short)d1;
        dd.z = (unsigned short)d2; dd.w = (unsigned short)d3;
        code4[p] = cc;
        code4[q] = dd;
    }
    {   // tail: element 8
        int p = base + 8 * stride;
        float4 r = img4[p], g = img4[p + total4], b = img4[p + 2 * total4];
        float4 gy;
        gy.x = grayf(r.x, g.x, b.x); gy.y = grayf(r.y, g.y, b.y);
        gy.z = grayf(r.z, g.z, b.z); gy.w = grayf(r.w, g.w, b.w);
        gray4[p] = gy;
        int c0 = qcode(r.x, g.x, b.x), c1 = qcode(r.y, g.y, b.y);
        int c2 = qcode(r.z, g.z, b.z), c3 = qcode(r.w, g.w, b.w);
        atomicAdd(&lh[c0 >> 1], (c0 & 1) ? 0x10000u : 1u);
        atomicAdd(&lh[c1 >> 1], (c1 & 1) ? 0x10000u : 1u);
        atomicAdd(&lh[c2 >> 1], (c2 & 1) ? 0x10000u : 1u);
        atomicAdd(&lh[c3 >> 1], (c3 & 1) ? 0x10000u : 1u);
        ushort4 cc;
        cc.x = (unsigned short)c0; cc.y = (unsigned short)c1;
        cc.z = (unsigned short)c2; cc.w = (unsigned short)c3;
        code4[p] = cc;
    }
    __syncthreads();
    unsigned* dst = parthist + (size_t)blockIdx.x * 16384;
    for (int t = threadIdx.x; t < 16384; t += 1024) dst[t] = lh[t];
}

// ---------------- pass 2: reduce partials -> hist + cstab + max/min-nonzero ----------------
__global__ void k_reduce(const unsigned* __restrict__ parthist, unsigned* __restrict__ hist,
                         float* __restrict__ cstab, unsigned* __restrict__ scal) {
    int b = blockIdx.x * blockDim.x + threadIdx.x;  // 0..16383 (bin pair)
    unsigned lo = 0u, hi = 0u;
#pragma unroll 4
    for (int k = 0; k < 256; k++) {
        unsigned v = parthist[(size_t)k * 16384 + b];
        lo += v & 0xFFFFu;
        hi += v >> 16;
    }
    hist[2 * b] = lo;
    hist[2 * b + 1] = hi;
    const float N = (float)NPIX;
    // identical expression to the per-pixel original
    cstab[2 * b]     = -logf((float)lo / N + 1e-9f) * 1.5f;
    cstab[2 * b + 1] = -logf((float)hi / N + 1e-9f) * 1.5f;
    unsigned mx = max(lo, hi);
    unsigned mn = 0xFFFFFFFFu;
    if (lo) mn = lo;
    if (hi) mn = min(mn, hi);
#pragma unroll
    for (int o = 32; o > 0; o >>= 1) {
        mx = max(mx, (unsigned)__shfl_down((int)mx, o));
        mn = min(mn, (unsigned)__shfl_down((int)mn, o));
    }
    __shared__ unsigned smx[4], smn[4];
    int lane = threadIdx.x & 63, wv = threadIdx.x >> 6;
    if (lane == 0) { smx[wv] = mx; smn[wv] = mn; }
    __syncthreads();
    if (threadIdx.x == 0) {
        unsigned a = max(max(smx[0], smx[1]), max(smx[2], smx[3]));
        unsigned c = min(min(smn[0], smn[1]), min(smn[2], smn[3]));
        atomicMax(&scal[3], a);
        atomicMin(&scal[4], c);
    }
}

// generic block max/min -> global atomics (supports 256 or 512 threads)
__device__ __forceinline__ void blockMaxMinAtomic(float vmax, float vmin,
                                                  unsigned* pmax, unsigned* pmin) {
#pragma unroll
    for (int o = 32; o > 0; o >>= 1) {
        vmax = fmaxf(vmax, __shfl_down(vmax, o));
        vmin = fminf(vmin, __shfl_down(vmin, o));
    }
    __shared__ float smax[8], smin[8];
    int lane = threadIdx.x & 63, wv = threadIdx.x >> 6;
    if (lane == 0) { smax[wv] = vmax; smin[wv] = vmin; }
    __syncthreads();
    if (threadIdx.x == 0) {
        int nw = blockDim.x >> 6;
        float a = smax[0], b = smin[0];
        for (int k = 1; k < nw; k++) { a = fmaxf(a, smax[k]); b = fminf(b, smin[k]); }
        if (pmax) atomicMax(pmax, __float_as_uint(a));
        if (pmin) atomicMin(pmin, __float_as_uint(b));
    }
}

// ---------------- pass 3: fused 5x5 box + sobel + mag + magmax ----------------
#define BS_W 256
#define BS_H 24
#define GTW 264
#define GTH 30
#define BLW 260
#define BLH 26
__global__ __launch_bounds__(512) void k_boxsobel(const float* __restrict__ g,
                                                  float* __restrict__ mag,
                                                  unsigned* __restrict__ scal) {
    __shared__ float GT[GTH * GTW];  // 31.7 KB
    __shared__ float BL[BLH * BLW];  // 27.0 KB
    int tid = threadIdx.x;
    int x0 = blockIdx.x * BS_W;
    int y0 = blockIdx.y * BS_H;
    for (int t = tid; t < GTH * GTW; t += 512) {
        int ly = t / GTW, lx = t - ly * GTW;
        int y = y0 - 3 + ly, x = x0 - 3 + lx;
        GT[t] = ((unsigned)y < TH && (unsigned)x < TW) ? g[(size_t)y * TW + x] : 0.f;
    }
    __syncthreads();
    // blurred: exact 25-term row-major order; 0 outside image (reference
    // zero-pads BLURRED for sobel, not gray)
    for (int t = tid; t < BLH * 65; t += 512) {
        int by = t / 65, gx = t - by * 65;
        int c0 = gx * 4;
        float acc[4] = {0.f, 0.f, 0.f, 0.f};
#pragma unroll
        for (int a = 0; a < 5; a++) {
            const float* rp = &GT[(by + a) * GTW + c0];
            float4 A = *(const float4*)rp;
            float4 B = *(const float4*)(rp + 4);
            float v[8] = {A.x, A.y, A.z, A.w, B.x, B.y, B.z, B.w};
#pragma unroll
            for (int j = 0; j < 4; j++)
#pragma unroll
                for (int b = 0; b < 5; b++)
                    acc[j] = __fadd_rn(acc[j], __fmul_rn(v[j + b], 0.04f));
        }
        int yb = y0 - 1 + by;
        float4 o;
        float* ov = (float*)&o;
#pragma unroll
        for (int j = 0; j < 4; j++) {
            int xb = x0 - 1 + c0 + j;
            ov[j] = ((unsigned)yb < TH && (unsigned)xb < TW) ? acc[j] : 0.f;
        }
        *(float4*)&BL[by * BLW + c0] = o;
    }
    __syncthreads();
    float tmax = 0.f;
    for (int t = tid; t < 24 * 64; t += 512) {
        int oy = t >> 6, gx = t & 63;
        int c0 = gx * 4;
        float v[3][6];
#pragma unroll
        for (int a = 0; a < 3; a++) {
            const float* rp = &BL[(oy + a) * BLW + c0];
            float4 P = *(const float4*)rp;
            float2 Q = *(const float2*)(rp + 4);
            v[a][0] = P.x; v[a][1] = P.y; v[a][2] = P.z; v[a][3] = P.w;
            v[a][4] = Q.x; v[a][5] = Q.y;
        }
        float4 mo;
        float* mv = (float*)&mo;
#pragma unroll
        for (int j = 0; j < 4; j++) {
            float gxv = 0.f;
            gxv = __fadd_rn(gxv, __fmul_rn(-1.f, v[0][j + 0]));
            gxv = __fadd_rn(gxv, v[0][j + 2]);
            gxv = __fadd_rn(gxv, __fmul_rn(-2.f, v[1][j + 0]));
            gxv = __fadd_rn(gxv, __fmul_rn(2.f, v[1][j + 2]));
            gxv = __fadd_rn(gxv, __fmul_rn(-1.f, v[2][j + 0]));
            gxv = __fadd_rn(gxv, v[2][j + 2]);
            float gyv = 0.f;
            gyv = __fadd_rn(gyv, __fmul_rn(-1.f, v[0][j + 0]));
            gyv = __fadd_rn(gyv, __fmul_rn(-2.f, v[0][j + 1]));
            gyv = __fadd_rn(gyv, __fmul_rn(-1.f, v[0][j + 2]));
            gyv = __fadd_rn(gyv, v[2][j + 0]);
            gyv = __fadd_rn(gyv, __fmul_rn(2.f, v[2][j + 1]));
            gyv = __fadd_rn(gyv, v[2][j + 2]);
            float m = sqrtf(__fadd_rn(__fmul_rn(gxv, gxv), __fmul_rn(gyv, gyv)));
            mv[j] = m;
            tmax = fmaxf(tmax, m);
        }
        *(float4*)&mag[(size_t)(y0 + oy) * TW + x0 + c0] = mo;
    }
    blockMaxMinAtomic(tmax, 0.f, &scal[0], nullptr);
}

// ---------------- pass 4: fused threshold + H-gauss + V-gauss + ed min/max ----------------
// tile: 256 cols x 48 out rows; edge map 1 bit/px packed via wave __ballot.
#define GS_W 256
#define GS_H 48
#define E_H 62
#define EWB 10
__global__ __launch_bounds__(512) void k_gauss(const float* __restrict__ mag,
                                               float* __restrict__ ed,
                                               const unsigned* __restrict__ scal,
                                               unsigned* __restrict__ scalw) {
    __shared__ float wt[15];
    __shared__ unsigned E8[E_H * EWB];   // 2.4 KB bit-packed edge map
    __shared__ float EH[E_H * GS_W];     // 63.5 KB
    if (threadIdx.x == 0) {
        float w[15];
        float s = 0.f;
        for (int t = 0; t < 15; t++) {
            int c = t - 7;
            w[t] = expf(-(float)(c * c) * 0.125f);
            s += w[t];
        }
        for (int t = 0; t < 15; t++) wt[t] = w[t] / s;
    }
    __syncthreads();
    float magmax = __uint_as_float(scal[0]);
    float hi = __fmul_rn(magmax, 0.2f);
    float lo = __fmul_rn(hi, 0.3f);
    int tid = threadIdx.x;
    int lane = tid & 63, wave = tid >> 6;  // 8 waves
    int x0 = blockIdx.x * GS_W;
    int y0 = blockIdx.y * GS_H;
    // stage thresholded edge map, 1 bit/px via ballot; 0 outside image / col>=270.
    // work item = (row, 64-col chunk): 62 rows x 5 chunks.
    for (int item = wave; item < E_H * 5; item += 8) {
        int ly = item / 5, ch = item - ly * 5;
        int y = y0 - 7 + ly;
        int lx = ch * 64 + lane;
        int x = x0 - 7 + lx;
        float m = ((unsigned)y < TH && lx < 270 && (unsigned)x < TW)
                      ? mag[(size_t)y * TW + x] : 0.f;
        unsigned long long mask = __ballot(m > lo && m < hi);
        if (lane < 2) E8[ly * EWB + ch * 2 + lane] = (unsigned)(mask >> (32 * lane));
    }
    __syncthreads();
    // horizontal 15-tap: 62 rows x 64 groups of 4 cols; 2 b32 reads/group
    for (int t = tid; t < E_H * 64; t += 512) {
        int ly = t >> 6, gx = t & 63;
        int c0 = gx * 4;
        int w0 = c0 >> 5, sh = c0 & 31;
        unsigned lo32 = E8[ly * EWB + w0];
        unsigned hi32 = E8[ly * EWB + w0 + 1];
        unsigned long long win = (((unsigned long long)hi32 << 32) | lo32) >> sh;
        float e[18];
#pragma unroll
        for (int j = 0; j < 18; j++) e[j] = (float)((unsigned)(win >> j) & 1u);
        float4 o;
        float* ov = (float*)&o;
#pragma unroll
        for (int j = 0; j < 4; j++) {
            float acc = 0.f;
#pragma unroll
            for (int k = 0; k < 15; k++) acc = fmaf(e[j + k], wt[k], acc);
            ov[j] = acc;
        }
        *(float4*)&EH[ly * GS_W + c0] = o;
    }
    __syncthreads();
    // vertical 15-tap + min/max: 48 rows x 64 groups of 4; 15 b128 reads/group
    float tmin = INFINITY, tmax = 0.f;
    for (int t = tid; t < GS_H * 64; t += 512) {
        int r = t >> 6, gx = t & 63;
        int c0 = gx * 4;
        float a0 = 0.f, a1 = 0.f, a2 = 0.f, a3 = 0.f;
#pragma unroll
        for (int k = 0; k < 15; k++) {
            float4 v = *(const float4*)&EH[(r + k) * GS_W + c0];
            a0 = fmaf(v.x, wt[k], a0);
            a1 = fmaf(v.y, wt[k], a1);
            a2 = fmaf(v.z, wt[k], a2);
            a3 = fmaf(v.w, wt[k], a3);
        }
        float4 o; o.x = a0; o.y = a1; o.z = a2; o.w = a3;
        *(float4*)&ed[(size_t)(y0 + r) * TW + x0 + c0] = o;
        tmin = fminf(tmin, fminf(fminf(a0, a1), fminf(a2, a3)));
        tmax = fmaxf(tmax, fmaxf(fmaxf(a0, a1), fmaxf(a2, a3)));
    }
    blockMaxMinAtomic(tmax, tmin, &scalw[2], &scalw[1]);
}

// ---------------- pass 5: normalize + color sparsity + sigmoid (vectorized) ----------------
__global__ void k_final(float4* __restrict__ io4, const ushort4* __restrict__ code4,
                        const float* __restrict__ cstab, const unsigned* __restrict__ scal,
                        const float* __restrict__ alphap, const float* __restrict__ betap) {
    float edmin = __uint_as_float(scal[1]);
    float edmax = __uint_as_float(scal[2]);
    float edrange = edmax - edmin + 1e-9f;
    const float N = (float)NPIX;
    float csmin = -logf((float)scal[3] / N + 1e-9f) * 1.5f;
    float csmax = -logf((float)scal[4] / N + 1e-9f) * 1.5f;
    float csrange = csmax - csmin + 1e-9f;
    float alpha = *alphap, beta = *betap;
    const int total4 = NPIX / 4;
    int stride = gridDim.x * blockDim.x;
    for (int p = blockIdx.x * blockDim.x + threadIdx.x; p < total4; p += stride) {
        float4 ed = io4[p];
        ushort4 cc = code4[p];
        float edv[4] = {ed.x, ed.y, ed.z, ed.w};
        unsigned short cv[4] = {cc.x, cc.y, cc.z, cc.w};
        float ov[4];
#pragma unroll
        for (int t = 0; t < 4; t++) {
            float en = (edv[t] - edmin) / edrange;
            float cs = cstab[cv[t]];
            float cn = (cs - csmin) / csrange;
            float x = alpha * en + beta * cn;
            ov[t] = 1.f / (1.f + expf(-x));
        }
        float4 o;
        o.x = ov[0]; o.y = ov[1]; o.z = ov[2]; o.w = ov[3];
        io4[p] = o;
    }
}

extern "C" void kernel_launch(void* const* d_in, const int* in_sizes, int n_in,
                              void* d_out, int out_size, void* d_ws, size_t ws_size,
                              hipStream_t stream) {
    const float* img = (const float*)d_in[0];
    const float* alphap = (const float*)d_in[1];
    const float* betap = (const float*)d_in[2];
    float* out = (float*)d_out;

    char* ws = (char*)d_ws;
    unsigned* scal = (unsigned*)ws;                                  // 64 B
    unsigned* hist = (unsigned*)(ws + 1024);                         // 128 KiB
    float* cstab = (float*)(ws + 1024 + 131072);                     // 128 KiB
    float* G = (float*)(ws + 524288);                                // 37.75 MB (gray)
    float* M = (float*)(ws + 524288 + (size_t)NPIX * 4);             // 37.75 MB (parthist -> mag)
    unsigned short* code = (unsigned short*)(ws + 524288 + (size_t)NPIX * 8);  // 18.9 MB
    unsigned* parthist = (unsigned*)M;  // 16 MB alias; dead before k_boxsobel writes mag

    hipLaunchKernelGGL(k_pre, dim3(256), dim3(1024), 0, stream,
                       (const float4*)img, (float4*)G, (ushort4*)code, parthist, scal);
    hipLaunchKernelGGL(k_reduce, dim3(64), dim3(256), 0, stream, parthist, hist, cstab, scal);
    hipLaunchKernelGGL(k_boxsobel, dim3(TW / BS_W, TH / BS_H), dim3(512), 0, stream,
                       G, M, scal);
    hipLaunchKernelGGL(k_gauss, dim3(TW / GS_W, TH / GS_H), dim3(512), 0, stream,
                       M, out, scal, scal);
    hipLaunchKernelGGL(k_final, dim3(2304), dim3(256), 0, stream, (float4*)out,
                       (const ushort4*)code, cstab, scal, alphap, betap);
}